// Round 8
// baseline (1694.188 us; speedup 1.0000x reference)
//
#include <hip/hip_runtime.h>
#include <hip/hip_bf16.h>

// GIN_34789235098229 — round 8: bucketed CSR build.
// Round 7 passed (1568 us, absmax 0.125). Profile: scatter_kernel = top
// dispatch, 285 us, 9% HBM, VALUBusy 0.4%, WRITE_SIZE 194 MB = E*64B ->
// every 4B scattered write dirties a full line; plus 3.2M atomic-return
// round trips on 100k random cursors. Fix: 32-node buckets (3125 = N/32):
//   count -> bucket histogram (3125 addrs)
//   bscan -> bucket offsets (single block)
//   bucket_scatter -> (dst,src) 8B pairs into bucket windows (~8KB hot)
//   bucket_deg -> per-bucket LDS counters, deg written contiguously
//   scan1/2/3 (unchanged) -> indptr, inv_deg
//   csr_fill -> per-bucket LDS cursors, esrc writes in ~4KB windows
// pairs buffer aliases node_pool (dead until first bn_pool; E*8 == N*64*4).
// Per-layer pipeline identical to round 7 (proven numerics).

typedef unsigned short ushort_t;
typedef unsigned int uint_t;

#define NN 100000
#define EE 3200000
#define GG 512
#define NBK 3125   // = NN/32 exactly; bucket = node >> 5

// ---------- detection ----------
__global__ __launch_bounds__(256) void detect_kernel(
    const uint_t* __restrict__ xw, const uint_t* __restrict__ ew,
    const uint_t* __restrict__ bw, int* __restrict__ flags)
{
    __shared__ int sb[256], se[256], sbb[256];
    int t = threadIdx.x;
    uint_t w = xw[t];
    uint_t eL = (w >> 7) & 0xffu;
    sb[t] = (eL >= 112u && eL <= 135u) ? 1 : 0;
    se[t] = (ew[2 * t + 1] == 0u) ? 1 : 0;
    sbb[t] = (bw[NN - 512 + 2 * t + 1] == 0u) ? 1 : 0;
    __syncthreads();
    for (int off = 128; off > 0; off >>= 1) {
        if (t < off) { sb[t] += sb[t + off]; se[t] += se[t + off]; sbb[t] += sbb[t + off]; }
        __syncthreads();
    }
    if (t == 0) {
        flags[0] = (sb[0] < 128) ? 1 : 0;   // 1 => fp32 floats
        flags[1] = (se[0] >= 128) ? 1 : 0;  // 1 => int64 edges
        flags[2] = (sbb[0] >= 128) ? 1 : 0; // 1 => int64 batch
    }
}

// ---------- canonicalization ----------
// wf layout (floats): [0,16384) W1 | [16384,32768) W2 | [32768,33024) b1 |
// [33024,33280) b2 | [33280,33536) gamma | [33536,33792) beta
__global__ __launch_bounds__(256) void cvt_w_kernel(
    const void* __restrict__ W1, const void* __restrict__ b1,
    const void* __restrict__ W2, const void* __restrict__ b2,
    const void* __restrict__ g, const void* __restrict__ be,
    const int* __restrict__ flags, float* __restrict__ wf)
{
    int i = blockIdx.x * 256 + threadIdx.x;
    if (i >= 33792) return;
    const void* src; int off;
    if (i < 16384)      { src = W1; off = i; }
    else if (i < 32768) { src = W2; off = i - 16384; }
    else if (i < 33024) { src = b1; off = i - 32768; }
    else if (i < 33280) { src = b2; off = i - 33024; }
    else if (i < 33536) { src = g;  off = i - 33280; }
    else                { src = be; off = i - 33536; }
    float v = flags[0] ? ((const float*)src)[off]
                       : __bfloat162float(((const __hip_bfloat16*)src)[off]);
    wf[i] = v;
}

__global__ __launch_bounds__(256) void cvt_x_kernel(
    const void* __restrict__ x, const int* __restrict__ flags,
    float* __restrict__ h, ushort_t* __restrict__ hb, int total)
{
    int i = blockIdx.x * 256 + threadIdx.x;
    if (i >= total) return;
    float v;
    ushort_t bits;
    if (flags[0]) {
        v = ((const float*)x)[i];
        __hip_bfloat16 b = __float2bfloat16(v);
        bits = *(ushort_t*)&b;
    } else {
        bits = ((const ushort_t*)x)[i];
        uint_t u = (uint_t)bits << 16;
        v = __uint_as_float(u);
    }
    h[i] = v;
    hb[i] = bits;
}

__global__ __launch_bounds__(256) void cvt_batch_kernel(
    const int* __restrict__ bw, const int* __restrict__ flags,
    int* __restrict__ b32, int n)
{
    int i = blockIdx.x * 256 + threadIdx.x;
    if (i >= n) return;
    b32[i] = flags[2] ? bw[2 * i] : bw[i];
}

// ---------- bucketed CSR build ----------
// bucket histogram (3125 addrs) + per-graph node counts (512 addrs)
__global__ __launch_bounds__(256) void count_kernel(
    const int* __restrict__ ei, const int* __restrict__ flags,
    const int* __restrict__ b32,
    int* __restrict__ bktcnt, int* __restrict__ gcnt, int E, int N)
{
    int i = blockIdx.x * 256 + threadIdx.x;
    int i64 = flags[1];
    if (i < E) {
        int d = i64 ? ei[2 * (E + i)] : ei[E + i];
        atomicAdd(&bktcnt[d >> 5], 1);
    }
    if (i < N) atomicAdd(&gcnt[b32[i]], 1);
}

// single-block exclusive scan of bucket counts -> bktoff[0..NBK], bktcur copy
__global__ __launch_bounds__(1024) void bscan_kernel(
    const int* __restrict__ bktcnt, int* __restrict__ bktoff,
    int* __restrict__ bktcur)
{
    __shared__ int sd[1024];
    int t = threadIdx.x;
    int base = t * 4;
    int v0 = 0, v1 = 0, v2 = 0, v3 = 0;
    if (base < NBK)     v0 = bktcnt[base];
    if (base + 1 < NBK) v1 = bktcnt[base + 1];
    if (base + 2 < NBK) v2 = bktcnt[base + 2];
    if (base + 3 < NBK) v3 = bktcnt[base + 3];
    int s = v0 + v1 + v2 + v3;
    sd[t] = s;
    __syncthreads();
    #pragma unroll
    for (int off = 1; off < 1024; off <<= 1) {
        int add = (t >= off) ? sd[t - off] : 0;
        __syncthreads();
        sd[t] += add;
        __syncthreads();
    }
    int excl = sd[t] - s;
    if (base < NBK)     { bktoff[base] = excl;     bktcur[base] = excl;     }
    excl += v0;
    if (base + 1 < NBK) { bktoff[base + 1] = excl; bktcur[base + 1] = excl; }
    excl += v1;
    if (base + 2 < NBK) { bktoff[base + 2] = excl; bktcur[base + 2] = excl; }
    excl += v2;
    if (base + 3 < NBK) { bktoff[base + 3] = excl; bktcur[base + 3] = excl; }
    if (t == 1023) bktoff[NBK] = sd[1023];
}

// scatter (dst,src) pairs into bucket windows (8B coalescing-friendly)
__global__ __launch_bounds__(256) void bucket_scatter_kernel(
    const int* __restrict__ ei, const int* __restrict__ flags,
    int* __restrict__ bktcur, int2* __restrict__ pairs, int E)
{
    int e = blockIdx.x * 256 + threadIdx.x;
    if (e >= E) return;
    int i64 = flags[1];
    int d = i64 ? ei[2 * (E + e)] : ei[E + e];
    int s = i64 ? ei[2 * e]       : ei[e];
    int p = atomicAdd(&bktcur[d >> 5], 1);
    pairs[p] = make_int2(d, s);
}

// per-bucket degree via LDS counters; deg written contiguously, no atomics
__global__ __launch_bounds__(256) void bucket_deg_kernel(
    const int2* __restrict__ pairs, const int* __restrict__ bktoff,
    int* __restrict__ deg)
{
    __shared__ int cnt[32];
    int b = blockIdx.x;
    int t = threadIdx.x;
    if (t < 32) cnt[t] = 0;
    __syncthreads();
    int e0 = bktoff[b], e1 = bktoff[b + 1];
    for (int i = e0 + t; i < e1; i += 256)
        atomicAdd(&cnt[pairs[i].x & 31], 1);
    __syncthreads();
    if (t < 32) deg[b * 32 + t] = cnt[t];
}

__global__ __launch_bounds__(256) void scan1_kernel(
    const int* __restrict__ deg, int* __restrict__ part, int* __restrict__ bsum, int n)
{
    __shared__ int sd[256];
    int t = threadIdx.x;
    int i0 = blockIdx.x * 1024 + t * 4;
    int v0 = 0, v1 = 0, v2 = 0, v3 = 0;
    if (i0 + 3 < n) {
        int4 v = *(const int4*)(deg + i0);
        v0 = v.x; v1 = v.y; v2 = v.z; v3 = v.w;
    } else if (i0 < n) {
        v0 = deg[i0];
        if (i0 + 1 < n) v1 = deg[i0 + 1];
        if (i0 + 2 < n) v2 = deg[i0 + 2];
    }
    int s = v0 + v1 + v2 + v3;
    sd[t] = s;
    __syncthreads();
    #pragma unroll
    for (int off = 1; off < 256; off <<= 1) {
        int add = (t >= off) ? sd[t - off] : 0;
        __syncthreads();
        sd[t] += add;
        __syncthreads();
    }
    int incl = sd[t];
    int e0 = incl - s;
    int p0 = e0 + v0, p1 = p0 + v1, p2 = p1 + v2, p3 = p2 + v3;
    if (i0 < n)     part[i0]     = p0;
    if (i0 + 1 < n) part[i0 + 1] = p1;
    if (i0 + 2 < n) part[i0 + 2] = p2;
    if (i0 + 3 < n) part[i0 + 3] = p3;
    if (t == 255) bsum[blockIdx.x] = incl;
}

__global__ __launch_bounds__(128) void scan2_kernel(int* __restrict__ bsum, int nb)
{
    __shared__ int sd[128];
    int t = threadIdx.x;
    int own = (t < nb) ? bsum[t] : 0;
    sd[t] = own;
    __syncthreads();
    #pragma unroll
    for (int off = 1; off < 128; off <<= 1) {
        int add = (t >= off) ? sd[t - off] : 0;
        __syncthreads();
        sd[t] += add;
        __syncthreads();
    }
    if (t < nb) bsum[t] = sd[t] - own;
}

__global__ __launch_bounds__(256) void scan3_kernel(
    const int* __restrict__ part, const int* __restrict__ bsum,
    const int* __restrict__ deg, int* __restrict__ indptr,
    float* __restrict__ inv_deg, int n)
{
    int i = blockIdx.x * 256 + threadIdx.x;
    if (i >= n) return;
    int val = part[i] + bsum[i >> 10];
    indptr[i + 1] = val;
    int d = deg[i];
    inv_deg[i] = (d > 0) ? 1.0f / (float)d : 0.0f;
    if (i == 0) indptr[0] = 0;
}

__global__ __launch_bounds__(512) void invg_kernel(
    const int* __restrict__ gcnt, float* __restrict__ invg, int G)
{
    int g = threadIdx.x;
    if (g < G) {
        int c = gcnt[g];
        invg[g] = (c > 0) ? 1.0f / (float)c : 0.0f;
    }
}

// per-bucket CSR fill via LDS cursors; esrc writes land in the bucket's
// contiguous [indptr[b*32], indptr[b*32+32]) window (~4KB)
__global__ __launch_bounds__(256) void csr_fill_kernel(
    const int2* __restrict__ pairs, const int* __restrict__ bktoff,
    const int* __restrict__ indptr, int* __restrict__ esrc)
{
    __shared__ int cur[32];
    int b = blockIdx.x;
    int t = threadIdx.x;
    if (t < 32) cur[t] = indptr[b * 32 + t];
    __syncthreads();
    int e0 = bktoff[b], e1 = bktoff[b + 1];
    for (int i = e0 + t; i < e1; i += 256) {
        int2 e = pairs[i];
        int p = atomicAdd(&cur[e.x & 31], 1);
        esrc[p] = e.y;
    }
}

// ---------- per-layer ----------
// 16 lanes/node, 4 feats/lane; neighbors from bf16 mirror (8 B/lane),
// own row fp32, z written fp32.
__global__ __launch_bounds__(256) void agg_kernel(
    const float* __restrict__ h, const ushort_t* __restrict__ hb,
    const int* __restrict__ indptr, const int* __restrict__ esrc,
    const float* __restrict__ inv_deg, float* __restrict__ zf, int n)
{
    int t = threadIdx.x;
    int grp = t >> 4, l = t & 15;
    int node = blockIdx.x * 16 + grp;
    if (node >= n) return;
    int e = indptr[node], end = indptr[node + 1];
    float a0 = 0.f, a1 = 0.f, a2 = 0.f, a3 = 0.f;
    const ushort_t* hbl = hb + l * 4;
    for (; e < end; ++e) {
        int s = esrc[e];
        uint2 v = *(const uint2*)(hbl + (size_t)s * 64);
        a0 += __uint_as_float(v.x << 16);
        a1 += __uint_as_float(v.x & 0xffff0000u);
        a2 += __uint_as_float(v.y << 16);
        a3 += __uint_as_float(v.y & 0xffff0000u);
    }
    float idg = inv_deg[node];
    float4 own = *(const float4*)(h + (size_t)node * 64 + l * 4);
    float4 r;
    r.x = fmaf(idg, a0, own.x);
    r.y = fmaf(idg, a1, own.y);
    r.z = fmaf(idg, a2, own.z);
    r.w = fmaf(idg, a3, own.w);
    *(float4*)(zf + (size_t)node * 64 + l * 4) = r;
}

// z <- relu(relu(z@W1+b1)@W2+b2) in place; fp32, thread-per-node, spill-free.
__global__ __launch_bounds__(256, 2) void mlp_kernel(
    float* __restrict__ zf,
    const float* __restrict__ W1f, const float* __restrict__ b1f,
    const float* __restrict__ W2f, const float* __restrict__ b2f,
    int n)
{
    __shared__ float w1s[4096];
    __shared__ float w2s[4096];
    __shared__ float bs[128];
    int t = threadIdx.x;
    for (int i = t; i < 4096; i += 256) {
        w1s[i] = W1f[i];
        w2s[i] = W2f[i];
    }
    if (t < 64) bs[t] = b1f[t];
    else if (t < 128) bs[t] = b2f[t - 64];
    __syncthreads();

    int node = blockIdx.x * 256 + t;
    if (node >= n) return;
    float* zrow = zf + (size_t)node * 64;

    float y[64];
    #pragma unroll
    for (int j = 0; j < 64; ++j) y[j] = bs[j];
    #pragma unroll
    for (int kb = 0; kb < 4; ++kb) {
        float4 c0 = *(const float4*)(zrow + kb * 16);
        float4 c1 = *(const float4*)(zrow + kb * 16 + 4);
        float4 c2 = *(const float4*)(zrow + kb * 16 + 8);
        float4 c3 = *(const float4*)(zrow + kb * 16 + 12);
        float zc[16] = {c0.x, c0.y, c0.z, c0.w, c1.x, c1.y, c1.z, c1.w,
                        c2.x, c2.y, c2.z, c2.w, c3.x, c3.y, c3.z, c3.w};
        #pragma unroll
        for (int k = 0; k < 16; ++k) {
            float a = zc[k];
            const float4* w = (const float4*)(w1s + (kb * 16 + k) * 64);
            #pragma unroll
            for (int q = 0; q < 16; ++q) {
                float4 wv = w[q];
                y[4*q]   = fmaf(a, wv.x, y[4*q]);
                y[4*q+1] = fmaf(a, wv.y, y[4*q+1]);
                y[4*q+2] = fmaf(a, wv.z, y[4*q+2]);
                y[4*q+3] = fmaf(a, wv.w, y[4*q+3]);
            }
        }
    }
    #pragma unroll
    for (int j = 0; j < 64; ++j) y[j] = fmaxf(y[j], 0.f);

    #pragma unroll
    for (int jb = 0; jb < 4; ++jb) {
        float o[16];
        #pragma unroll
        for (int q = 0; q < 16; ++q) o[q] = bs[64 + jb * 16 + q];
        #pragma unroll
        for (int k = 0; k < 64; ++k) {
            float a = y[k];
            const float4* w = (const float4*)(w2s + k * 64 + jb * 16);
            #pragma unroll
            for (int q = 0; q < 4; ++q) {
                float4 wv = w[q];
                o[4*q]   = fmaf(a, wv.x, o[4*q]);
                o[4*q+1] = fmaf(a, wv.y, o[4*q+1]);
                o[4*q+2] = fmaf(a, wv.z, o[4*q+2]);
                o[4*q+3] = fmaf(a, wv.w, o[4*q+3]);
            }
        }
        #pragma unroll
        for (int q = 0; q < 4; ++q) {
            float4 v;
            v.x = fmaxf(o[4*q],   0.f);
            v.y = fmaxf(o[4*q+1], 0.f);
            v.z = fmaxf(o[4*q+2], 0.f);
            v.w = fmaxf(o[4*q+3], 0.f);
            *(float4*)(zrow + jb * 16 + q * 4) = v;
        }
    }
}

// per-feature sum / sumsq -> float atomics (128 addresses)
__global__ __launch_bounds__(256) void stats_kernel(
    const float* __restrict__ z, float* __restrict__ stats, int N)
{
    __shared__ float ssum[256], ssq[256];
    int t = threadIdx.x;
    float s = 0.f, q = 0.f;
    int total = N * 64;
    for (int i = blockIdx.x * 256 + t; i < total; i += 256 * gridDim.x) {
        float v = z[i];
        s += v;
        q += v * v;
    }
    ssum[t] = s; ssq[t] = q;
    __syncthreads();
    if (t < 64) {
        float S = ssum[t] + ssum[t+64] + ssum[t+128] + ssum[t+192];
        float Q = ssq[t]  + ssq[t+64]  + ssq[t+128]  + ssq[t+192];
        atomicAdd(&stats[t], S);
        atomicAdd(&stats[64 + t], Q);
    }
}

__global__ __launch_bounds__(64) void bnfin_kernel(
    const float* __restrict__ stats, const float* __restrict__ gammaf,
    const float* __restrict__ betaf, float* __restrict__ ac, int N)
{
    int f = threadIdx.x;
    if (f >= 64) return;
    float invN = 1.0f / (float)N;
    float mu = stats[f] * invN;
    float var = stats[64 + f] * invN - mu * mu;
    if (var < 0.f) var = 0.f;
    float inv = rsqrtf(var + 1e-5f);
    float A = gammaf[f] * inv;
    float C = betaf[f] - mu * A;
    ac[f] = A;
    ac[64 + f] = C;
}

__global__ __launch_bounds__(256) void bn_pool_kernel(
    const float* __restrict__ z, float* __restrict__ h,
    ushort_t* __restrict__ hb, float* __restrict__ node_pool,
    const int* __restrict__ b32, const float* __restrict__ ac,
    float* __restrict__ gpool, int N, int first)
{
    int wave = (blockIdx.x * 256 + threadIdx.x) >> 6;
    int f = threadIdx.x & 63;
    int n0 = wave * 64;
    if (n0 >= N) return;
    int n1 = min(n0 + 64, N);
    float A = ac[f], C = ac[64 + f];
    float racc = 0.f;
    int cur = b32[n0];
    for (int n = n0; n < n1; ++n) {
        int g = b32[n];
        if (g != cur) {  // wave-uniform branch
            atomicAdd(&gpool[(size_t)cur * 64 + f], racc);
            racc = 0.f;
            cur = g;
        }
        size_t idx = (size_t)n * 64 + f;
        float hv = fmaf(z[idx], A, C);
        h[idx] = hv;
        __hip_bfloat16 b = __float2bfloat16(hv);
        hb[idx] = *(ushort_t*)&b;
        float np = first ? hv : (node_pool[idx] + hv);
        node_pool[idx] = np;
        racc += hv;
    }
    atomicAdd(&gpool[(size_t)cur * 64 + f], racc);
}

__global__ __launch_bounds__(256) void finalize_kernel(
    const float* __restrict__ node_pool, const float* __restrict__ gpool,
    const float* __restrict__ invg, const int* __restrict__ flags,
    void* __restrict__ out, int N)
{
    int i = blockIdx.x * 256 + threadIdx.x;
    int nd = N * 64;
    int total = nd + GG * 64;
    if (i >= total) return;
    float v;
    if (i < nd) v = node_pool[i];
    else { int j = i - nd; v = gpool[j] * invg[j >> 6]; }
    if (flags[0]) ((float*)out)[i] = v;
    else ((__hip_bfloat16*)out)[i] = __float2bfloat16(v);
}

extern "C" void kernel_launch(void* const* d_in, const int* in_sizes, int n_in,
                              void* d_out, int out_size, void* d_ws, size_t ws_size,
                              hipStream_t stream)
{
    constexpr int N = NN, E = EE, G = GG;
    constexpr int ND = N * 64;

    const void* x     = d_in[0];
    const void* W1    = d_in[1];
    const void* b1    = d_in[2];
    const void* W2    = d_in[3];
    const void* b2    = d_in[4];
    const void* gamma = d_in[5];
    const void* beta  = d_in[6];
    const int* ei     = (const int*)d_in[7];
    const int* batw   = (const int*)d_in[8];

    char* p = (char*)d_ws;
    auto alloc = [&](size_t bytes) -> char* {
        char* r = p;
        p += (bytes + 255) & ~(size_t)255;
        return r;
    };
    float*    hf        = (float*)alloc((size_t)ND * 4);
    float*    zf        = (float*)alloc((size_t)ND * 4);
    float*    node_pool = (float*)alloc((size_t)ND * 4);
    ushort_t* hb        = (ushort_t*)alloc((size_t)ND * 2);
    int*      esrc      = (int*)alloc((size_t)E * 4);
    int*      indptr    = (int*)alloc((size_t)(N + 1) * 4);
    int*      deg       = (int*)alloc((size_t)N * 4);
    int*      part      = (int*)alloc((size_t)N * 4);
    float*    invdeg    = (float*)alloc((size_t)N * 4);
    int*      b32       = (int*)alloc((size_t)N * 4);
    int*      bsum      = (int*)alloc(128 * 4);
    int*      gcnt      = (int*)alloc(G * 4);
    float*    invg      = (float*)alloc(G * 4);
    float*    gpool     = (float*)alloc((size_t)G * 64 * 4);
    float*    stats     = (float*)alloc(128 * 4);
    float*    ac        = (float*)alloc(128 * 4);
    float*    wf        = (float*)alloc(33792 * 4);
    int*      flags     = (int*)alloc(16 * 4);
    int*      bktcnt    = (int*)alloc((size_t)NBK * 4);
    int*      bktoff    = (int*)alloc((size_t)(NBK + 1) * 4);
    int*      bktcur    = (int*)alloc((size_t)NBK * 4);
    // pairs aliases node_pool: dead until first bn_pool; E*8 == ND*4 bytes
    int2*     pairs     = (int2*)node_pool;

    hipMemsetAsync(gcnt,   0, (size_t)G * 4,      stream);
    hipMemsetAsync(gpool,  0, (size_t)G * 64 * 4, stream);
    hipMemsetAsync(bktcnt, 0, (size_t)NBK * 4,    stream);

    detect_kernel<<<1, 256, 0, stream>>>(
        (const uint_t*)x, (const uint_t*)ei, (const uint_t*)batw, flags);
    cvt_w_kernel<<<132, 256, 0, stream>>>(W1, b1, W2, b2, gamma, beta, flags, wf);
    cvt_x_kernel<<<(ND + 255) / 256, 256, 0, stream>>>(x, flags, hf, hb, ND);
    cvt_batch_kernel<<<(N + 255) / 256, 256, 0, stream>>>(batw, flags, b32, N);
    count_kernel<<<(E + 255) / 256, 256, 0, stream>>>(ei, flags, b32, bktcnt, gcnt, E, N);
    bscan_kernel<<<1, 1024, 0, stream>>>(bktcnt, bktoff, bktcur);
    bucket_scatter_kernel<<<(E + 255) / 256, 256, 0, stream>>>(ei, flags, bktcur, pairs, E);
    bucket_deg_kernel<<<NBK, 256, 0, stream>>>(pairs, bktoff, deg);
    int nb = (N + 1023) / 1024;  // 98
    scan1_kernel<<<nb, 256, 0, stream>>>(deg, part, bsum, N);
    scan2_kernel<<<1, 128, 0, stream>>>(bsum, nb);
    scan3_kernel<<<(N + 255) / 256, 256, 0, stream>>>(part, bsum, deg, indptr, invdeg, N);
    invg_kernel<<<1, 512, 0, stream>>>(gcnt, invg, G);
    csr_fill_kernel<<<NBK, 256, 0, stream>>>(pairs, bktoff, indptr, esrc);

    for (int l = 0; l < 4; ++l) {
        agg_kernel<<<(N + 15) / 16, 256, 0, stream>>>(
            hf, hb, indptr, esrc, invdeg, zf, N);
        mlp_kernel<<<(N + 255) / 256, 256, 0, stream>>>(
            zf, wf + l * 4096, wf + 32768 + l * 64,
            wf + 16384 + l * 4096, wf + 33024 + l * 64, N);
        hipMemsetAsync(stats, 0, 128 * 4, stream);
        stats_kernel<<<256, 256, 0, stream>>>(zf, stats, N);
        bnfin_kernel<<<1, 64, 0, stream>>>(
            stats, wf + 33280 + l * 64, wf + 33536 + l * 64, ac, N);
        bn_pool_kernel<<<(N + 255) / 256, 256, 0, stream>>>(
            zf, hf, hb, node_pool, b32, ac, gpool, N, (l == 0) ? 1 : 0);
    }
    finalize_kernel<<<(ND + G * 64 + 255) / 256, 256, 0, stream>>>(
        node_pool, gpool, invg, flags, d_out, N);
}

// Round 9
// 1243.237 us; speedup vs baseline: 1.3627x; 1.3627x over previous
//
#include <hip/hip_runtime.h>
#include <hip/hip_bf16.h>

// GIN_34789235098229 — round 9: atomic-free CSR build.
// Round 8 (1694 us) revealed: device-scope global atomics run at ~11 G ops/s
// regardless of address spread (count 3.2M@3125addrs = 288 us ~= round-7
// scatter 3.2M@100k = 285 us). Round 8 had TWO edge-rate atomic kernels.
// Fix: zero global atomics at edge rate.
//   count_hist (256 blks): LDS histogram over 391 buckets(256 nodes) -> histo[j][b]
//   blockscan  (391 blks): excl scan histo[j][:] across blocks, tot[j]
//   bscan      (1 blk)   : excl scan tot -> bktoff
//   pair_scatter(256 blks): LDS cursors = histo[j][b]+bktoff[j]; per-(blk,bkt)
//                           writes CONTIGUOUS -> ~1.1x line amplification
//   bucket_deg/scan1-3/csr_fill: 256-node windows, LDS counters (as r8)
// gcnt atomics (node-rate, cheap) moved into cvt_batch.
// Per-layer pipeline identical to rounds 7/8 (proven numerics, absmax 0.125).

typedef unsigned short ushort_t;
typedef unsigned int uint_t;

#define NN 100000
#define EE 3200000
#define GG 512
#define NBK 391    // ceil(NN/256); bucket = node >> 8
#define NHB 256    // histogram blocks
#define ECHUNK 12500  // EE / NHB exactly

// ---------- detection ----------
__global__ __launch_bounds__(256) void detect_kernel(
    const uint_t* __restrict__ xw, const uint_t* __restrict__ ew,
    const uint_t* __restrict__ bw, int* __restrict__ flags)
{
    __shared__ int sb[256], se[256], sbb[256];
    int t = threadIdx.x;
    uint_t w = xw[t];
    uint_t eL = (w >> 7) & 0xffu;
    sb[t] = (eL >= 112u && eL <= 135u) ? 1 : 0;
    se[t] = (ew[2 * t + 1] == 0u) ? 1 : 0;
    sbb[t] = (bw[NN - 512 + 2 * t + 1] == 0u) ? 1 : 0;
    __syncthreads();
    for (int off = 128; off > 0; off >>= 1) {
        if (t < off) { sb[t] += sb[t + off]; se[t] += se[t + off]; sbb[t] += sbb[t + off]; }
        __syncthreads();
    }
    if (t == 0) {
        flags[0] = (sb[0] < 128) ? 1 : 0;   // 1 => fp32 floats
        flags[1] = (se[0] >= 128) ? 1 : 0;  // 1 => int64 edges
        flags[2] = (sbb[0] >= 128) ? 1 : 0; // 1 => int64 batch
    }
}

// ---------- canonicalization ----------
// wf layout (floats): [0,16384) W1 | [16384,32768) W2 | [32768,33024) b1 |
// [33024,33280) b2 | [33280,33536) gamma | [33536,33792) beta
__global__ __launch_bounds__(256) void cvt_w_kernel(
    const void* __restrict__ W1, const void* __restrict__ b1,
    const void* __restrict__ W2, const void* __restrict__ b2,
    const void* __restrict__ g, const void* __restrict__ be,
    const int* __restrict__ flags, float* __restrict__ wf)
{
    int i = blockIdx.x * 256 + threadIdx.x;
    if (i >= 33792) return;
    const void* src; int off;
    if (i < 16384)      { src = W1; off = i; }
    else if (i < 32768) { src = W2; off = i - 16384; }
    else if (i < 33024) { src = b1; off = i - 32768; }
    else if (i < 33280) { src = b2; off = i - 33024; }
    else if (i < 33536) { src = g;  off = i - 33280; }
    else                { src = be; off = i - 33536; }
    float v = flags[0] ? ((const float*)src)[off]
                       : __bfloat162float(((const __hip_bfloat16*)src)[off]);
    wf[i] = v;
}

__global__ __launch_bounds__(256) void cvt_x_kernel(
    const void* __restrict__ x, const int* __restrict__ flags,
    float* __restrict__ h, ushort_t* __restrict__ hb, int total)
{
    int i = blockIdx.x * 256 + threadIdx.x;
    if (i >= total) return;
    float v;
    ushort_t bits;
    if (flags[0]) {
        v = ((const float*)x)[i];
        __hip_bfloat16 b = __float2bfloat16(v);
        bits = *(ushort_t*)&b;
    } else {
        bits = ((const ushort_t*)x)[i];
        uint_t u = (uint_t)bits << 16;
        v = __uint_as_float(u);
    }
    h[i] = v;
    hb[i] = bits;
}

// batch -> b32, plus per-graph node counts (node-rate atomics, ~9 us)
__global__ __launch_bounds__(256) void cvt_batch_kernel(
    const int* __restrict__ bw, const int* __restrict__ flags,
    int* __restrict__ b32, int* __restrict__ gcnt, int n)
{
    int i = blockIdx.x * 256 + threadIdx.x;
    if (i >= n) return;
    int v = flags[2] ? bw[2 * i] : bw[i];
    b32[i] = v;
    atomicAdd(&gcnt[v], 1);
}

// ---------- atomic-free CSR build ----------
// 1) per-block LDS bucket histogram -> histo[j*NHB + b]
__global__ __launch_bounds__(256) void count_hist_kernel(
    const int* __restrict__ ei, const int* __restrict__ flags,
    int* __restrict__ histo, int E)
{
    __shared__ int lh[NBK];
    int b = blockIdx.x, t = threadIdx.x;
    for (int j = t; j < NBK; j += 256) lh[j] = 0;
    __syncthreads();
    int i64 = flags[1];
    int e0 = b * ECHUNK, e1 = min(e0 + ECHUNK, E);
    for (int i = e0 + t; i < e1; i += 256) {
        int d = i64 ? ei[2 * (E + i)] : ei[E + i];
        atomicAdd(&lh[d >> 8], 1);
    }
    __syncthreads();
    for (int j = t; j < NBK; j += 256) histo[j * NHB + b] = lh[j];
}

// 2) per-bucket exclusive scan across the NHB blocks (coalesced), tot[j]
__global__ __launch_bounds__(NHB) void blockscan_kernel(
    int* __restrict__ histo, int* __restrict__ tot)
{
    __shared__ int sd[NHB];
    int j = blockIdx.x, t = threadIdx.x;
    int v = histo[j * NHB + t];
    sd[t] = v;
    __syncthreads();
    #pragma unroll
    for (int off = 1; off < NHB; off <<= 1) {
        int add = (t >= off) ? sd[t - off] : 0;
        __syncthreads();
        sd[t] += add;
        __syncthreads();
    }
    histo[j * NHB + t] = sd[t] - v;  // exclusive within bucket
    if (t == NHB - 1) tot[j] = sd[NHB - 1];
}

// 3) exclusive scan of bucket totals -> bktoff[0..NBK]
__global__ __launch_bounds__(512) void bscan_kernel(
    const int* __restrict__ tot, int* __restrict__ bktoff)
{
    __shared__ int sd[512];
    int t = threadIdx.x;
    int v = (t < NBK) ? tot[t] : 0;
    sd[t] = v;
    __syncthreads();
    #pragma unroll
    for (int off = 1; off < 512; off <<= 1) {
        int add = (t >= off) ? sd[t - off] : 0;
        __syncthreads();
        sd[t] += add;
        __syncthreads();
    }
    if (t < NBK) bktoff[t] = sd[t] - v;
    if (t == 511) bktoff[NBK] = sd[511];
}

// 4) scatter pairs; LDS cursors seeded with deterministic global offsets ->
//    each block's writes within a bucket are contiguous (no global atomics)
__global__ __launch_bounds__(256) void pair_scatter_kernel(
    const int* __restrict__ ei, const int* __restrict__ flags,
    const int* __restrict__ histo, const int* __restrict__ bktoff,
    int2* __restrict__ pairs, int E)
{
    __shared__ int cur[NBK];
    int b = blockIdx.x, t = threadIdx.x;
    for (int j = t; j < NBK; j += 256) cur[j] = histo[j * NHB + b] + bktoff[j];
    __syncthreads();
    int i64 = flags[1];
    int e0 = b * ECHUNK, e1 = min(e0 + ECHUNK, E);
    for (int i = e0 + t; i < e1; i += 256) {
        int d = i64 ? ei[2 * (E + i)] : ei[E + i];
        int s = i64 ? ei[2 * i]       : ei[i];
        int p = atomicAdd(&cur[d >> 8], 1);
        pairs[p] = make_int2(d, s);
    }
}

// 5) per-bucket degree via LDS counters; deg written contiguously
__global__ __launch_bounds__(256) void bucket_deg_kernel(
    const int2* __restrict__ pairs, const int* __restrict__ bktoff,
    int* __restrict__ deg, int N)
{
    __shared__ int cnt[256];
    int j = blockIdx.x, t = threadIdx.x;
    cnt[t] = 0;
    __syncthreads();
    int e0 = bktoff[j], e1 = bktoff[j + 1];
    for (int i = e0 + t; i < e1; i += 256)
        atomicAdd(&cnt[pairs[i].x & 255], 1);
    __syncthreads();
    int idx = j * 256 + t;
    if (idx < N) deg[idx] = cnt[t];
}

__global__ __launch_bounds__(256) void scan1_kernel(
    const int* __restrict__ deg, int* __restrict__ part, int* __restrict__ bsum, int n)
{
    __shared__ int sd[256];
    int t = threadIdx.x;
    int i0 = blockIdx.x * 1024 + t * 4;
    int v0 = 0, v1 = 0, v2 = 0, v3 = 0;
    if (i0 + 3 < n) {
        int4 v = *(const int4*)(deg + i0);
        v0 = v.x; v1 = v.y; v2 = v.z; v3 = v.w;
    } else if (i0 < n) {
        v0 = deg[i0];
        if (i0 + 1 < n) v1 = deg[i0 + 1];
        if (i0 + 2 < n) v2 = deg[i0 + 2];
    }
    int s = v0 + v1 + v2 + v3;
    sd[t] = s;
    __syncthreads();
    #pragma unroll
    for (int off = 1; off < 256; off <<= 1) {
        int add = (t >= off) ? sd[t - off] : 0;
        __syncthreads();
        sd[t] += add;
        __syncthreads();
    }
    int incl = sd[t];
    int e0 = incl - s;
    int p0 = e0 + v0, p1 = p0 + v1, p2 = p1 + v2, p3 = p2 + v3;
    if (i0 < n)     part[i0]     = p0;
    if (i0 + 1 < n) part[i0 + 1] = p1;
    if (i0 + 2 < n) part[i0 + 2] = p2;
    if (i0 + 3 < n) part[i0 + 3] = p3;
    if (t == 255) bsum[blockIdx.x] = incl;
}

__global__ __launch_bounds__(128) void scan2_kernel(int* __restrict__ bsum, int nb)
{
    __shared__ int sd[128];
    int t = threadIdx.x;
    int own = (t < nb) ? bsum[t] : 0;
    sd[t] = own;
    __syncthreads();
    #pragma unroll
    for (int off = 1; off < 128; off <<= 1) {
        int add = (t >= off) ? sd[t - off] : 0;
        __syncthreads();
        sd[t] += add;
        __syncthreads();
    }
    if (t < nb) bsum[t] = sd[t] - own;
}

__global__ __launch_bounds__(256) void scan3_kernel(
    const int* __restrict__ part, const int* __restrict__ bsum,
    const int* __restrict__ deg, int* __restrict__ indptr,
    float* __restrict__ inv_deg, int n)
{
    int i = blockIdx.x * 256 + threadIdx.x;
    if (i >= n) return;
    int val = part[i] + bsum[i >> 10];
    indptr[i + 1] = val;
    int d = deg[i];
    inv_deg[i] = (d > 0) ? 1.0f / (float)d : 0.0f;
    if (i == 0) indptr[0] = 0;
}

__global__ __launch_bounds__(512) void invg_kernel(
    const int* __restrict__ gcnt, float* __restrict__ invg, int G)
{
    int g = threadIdx.x;
    if (g < G) {
        int c = gcnt[g];
        invg[g] = (c > 0) ? 1.0f / (float)c : 0.0f;
    }
}

// 6) per-bucket CSR fill via LDS cursors; esrc writes within ~4KB window
__global__ __launch_bounds__(256) void csr_fill_kernel(
    const int2* __restrict__ pairs, const int* __restrict__ bktoff,
    const int* __restrict__ indptr, int* __restrict__ esrc, int N)
{
    __shared__ int cur[256];
    int j = blockIdx.x, t = threadIdx.x;
    int idx = j * 256 + t;
    cur[t] = (idx < N) ? indptr[idx] : 0;
    __syncthreads();
    int e0 = bktoff[j], e1 = bktoff[j + 1];
    for (int i = e0 + t; i < e1; i += 256) {
        int2 e = pairs[i];
        int p = atomicAdd(&cur[e.x & 255], 1);
        esrc[p] = e.y;
    }
}

// ---------- per-layer ----------
// 16 lanes/node, 4 feats/lane; neighbors from bf16 mirror (8 B/lane),
// own row fp32, z written fp32.
__global__ __launch_bounds__(256) void agg_kernel(
    const float* __restrict__ h, const ushort_t* __restrict__ hb,
    const int* __restrict__ indptr, const int* __restrict__ esrc,
    const float* __restrict__ inv_deg, float* __restrict__ zf, int n)
{
    int t = threadIdx.x;
    int grp = t >> 4, l = t & 15;
    int node = blockIdx.x * 16 + grp;
    if (node >= n) return;
    int e = indptr[node], end = indptr[node + 1];
    float a0 = 0.f, a1 = 0.f, a2 = 0.f, a3 = 0.f;
    const ushort_t* hbl = hb + l * 4;
    for (; e < end; ++e) {
        int s = esrc[e];
        uint2 v = *(const uint2*)(hbl + (size_t)s * 64);
        a0 += __uint_as_float(v.x << 16);
        a1 += __uint_as_float(v.x & 0xffff0000u);
        a2 += __uint_as_float(v.y << 16);
        a3 += __uint_as_float(v.y & 0xffff0000u);
    }
    float idg = inv_deg[node];
    float4 own = *(const float4*)(h + (size_t)node * 64 + l * 4);
    float4 r;
    r.x = fmaf(idg, a0, own.x);
    r.y = fmaf(idg, a1, own.y);
    r.z = fmaf(idg, a2, own.z);
    r.w = fmaf(idg, a3, own.w);
    *(float4*)(zf + (size_t)node * 64 + l * 4) = r;
}

// z <- relu(relu(z@W1+b1)@W2+b2) in place; fp32, thread-per-node, spill-free.
__global__ __launch_bounds__(256, 2) void mlp_kernel(
    float* __restrict__ zf,
    const float* __restrict__ W1f, const float* __restrict__ b1f,
    const float* __restrict__ W2f, const float* __restrict__ b2f,
    int n)
{
    __shared__ float w1s[4096];
    __shared__ float w2s[4096];
    __shared__ float bs[128];
    int t = threadIdx.x;
    for (int i = t; i < 4096; i += 256) {
        w1s[i] = W1f[i];
        w2s[i] = W2f[i];
    }
    if (t < 64) bs[t] = b1f[t];
    else if (t < 128) bs[t] = b2f[t - 64];
    __syncthreads();

    int node = blockIdx.x * 256 + t;
    if (node >= n) return;
    float* zrow = zf + (size_t)node * 64;

    float y[64];
    #pragma unroll
    for (int j = 0; j < 64; ++j) y[j] = bs[j];
    #pragma unroll
    for (int kb = 0; kb < 4; ++kb) {
        float4 c0 = *(const float4*)(zrow + kb * 16);
        float4 c1 = *(const float4*)(zrow + kb * 16 + 4);
        float4 c2 = *(const float4*)(zrow + kb * 16 + 8);
        float4 c3 = *(const float4*)(zrow + kb * 16 + 12);
        float zc[16] = {c0.x, c0.y, c0.z, c0.w, c1.x, c1.y, c1.z, c1.w,
                        c2.x, c2.y, c2.z, c2.w, c3.x, c3.y, c3.z, c3.w};
        #pragma unroll
        for (int k = 0; k < 16; ++k) {
            float a = zc[k];
            const float4* w = (const float4*)(w1s + (kb * 16 + k) * 64);
            #pragma unroll
            for (int q = 0; q < 16; ++q) {
                float4 wv = w[q];
                y[4*q]   = fmaf(a, wv.x, y[4*q]);
                y[4*q+1] = fmaf(a, wv.y, y[4*q+1]);
                y[4*q+2] = fmaf(a, wv.z, y[4*q+2]);
                y[4*q+3] = fmaf(a, wv.w, y[4*q+3]);
            }
        }
    }
    #pragma unroll
    for (int j = 0; j < 64; ++j) y[j] = fmaxf(y[j], 0.f);

    #pragma unroll
    for (int jb = 0; jb < 4; ++jb) {
        float o[16];
        #pragma unroll
        for (int q = 0; q < 16; ++q) o[q] = bs[64 + jb * 16 + q];
        #pragma unroll
        for (int k = 0; k < 64; ++k) {
            float a = y[k];
            const float4* w = (const float4*)(w2s + k * 64 + jb * 16);
            #pragma unroll
            for (int q = 0; q < 4; ++q) {
                float4 wv = w[q];
                o[4*q]   = fmaf(a, wv.x, o[4*q]);
                o[4*q+1] = fmaf(a, wv.y, o[4*q+1]);
                o[4*q+2] = fmaf(a, wv.z, o[4*q+2]);
                o[4*q+3] = fmaf(a, wv.w, o[4*q+3]);
            }
        }
        #pragma unroll
        for (int q = 0; q < 4; ++q) {
            float4 v;
            v.x = fmaxf(o[4*q],   0.f);
            v.y = fmaxf(o[4*q+1], 0.f);
            v.z = fmaxf(o[4*q+2], 0.f);
            v.w = fmaxf(o[4*q+3], 0.f);
            *(float4*)(zrow + jb * 16 + q * 4) = v;
        }
    }
}

// per-feature sum / sumsq -> float atomics (128 addresses)
__global__ __launch_bounds__(256) void stats_kernel(
    const float* __restrict__ z, float* __restrict__ stats, int N)
{
    __shared__ float ssum[256], ssq[256];
    int t = threadIdx.x;
    float s = 0.f, q = 0.f;
    int total = N * 64;
    for (int i = blockIdx.x * 256 + t; i < total; i += 256 * gridDim.x) {
        float v = z[i];
        s += v;
        q += v * v;
    }
    ssum[t] = s; ssq[t] = q;
    __syncthreads();
    if (t < 64) {
        float S = ssum[t] + ssum[t+64] + ssum[t+128] + ssum[t+192];
        float Q = ssq[t]  + ssq[t+64]  + ssq[t+128]  + ssq[t+192];
        atomicAdd(&stats[t], S);
        atomicAdd(&stats[64 + t], Q);
    }
}

__global__ __launch_bounds__(64) void bnfin_kernel(
    const float* __restrict__ stats, const float* __restrict__ gammaf,
    const float* __restrict__ betaf, float* __restrict__ ac, int N)
{
    int f = threadIdx.x;
    if (f >= 64) return;
    float invN = 1.0f / (float)N;
    float mu = stats[f] * invN;
    float var = stats[64 + f] * invN - mu * mu;
    if (var < 0.f) var = 0.f;
    float inv = rsqrtf(var + 1e-5f);
    float A = gammaf[f] * inv;
    float C = betaf[f] - mu * A;
    ac[f] = A;
    ac[64 + f] = C;
}

__global__ __launch_bounds__(256) void bn_pool_kernel(
    const float* __restrict__ z, float* __restrict__ h,
    ushort_t* __restrict__ hb, float* __restrict__ node_pool,
    const int* __restrict__ b32, const float* __restrict__ ac,
    float* __restrict__ gpool, int N, int first)
{
    int wave = (blockIdx.x * 256 + threadIdx.x) >> 6;
    int f = threadIdx.x & 63;
    int n0 = wave * 64;
    if (n0 >= N) return;
    int n1 = min(n0 + 64, N);
    float A = ac[f], C = ac[64 + f];
    float racc = 0.f;
    int cur = b32[n0];
    for (int n = n0; n < n1; ++n) {
        int g = b32[n];
        if (g != cur) {  // wave-uniform branch
            atomicAdd(&gpool[(size_t)cur * 64 + f], racc);
            racc = 0.f;
            cur = g;
        }
        size_t idx = (size_t)n * 64 + f;
        float hv = fmaf(z[idx], A, C);
        h[idx] = hv;
        __hip_bfloat16 b = __float2bfloat16(hv);
        hb[idx] = *(ushort_t*)&b;
        float np = first ? hv : (node_pool[idx] + hv);
        node_pool[idx] = np;
        racc += hv;
    }
    atomicAdd(&gpool[(size_t)cur * 64 + f], racc);
}

__global__ __launch_bounds__(256) void finalize_kernel(
    const float* __restrict__ node_pool, const float* __restrict__ gpool,
    const float* __restrict__ invg, const int* __restrict__ flags,
    void* __restrict__ out, int N)
{
    int i = blockIdx.x * 256 + threadIdx.x;
    int nd = N * 64;
    int total = nd + GG * 64;
    if (i >= total) return;
    float v;
    if (i < nd) v = node_pool[i];
    else { int j = i - nd; v = gpool[j] * invg[j >> 6]; }
    if (flags[0]) ((float*)out)[i] = v;
    else ((__hip_bfloat16*)out)[i] = __float2bfloat16(v);
}

extern "C" void kernel_launch(void* const* d_in, const int* in_sizes, int n_in,
                              void* d_out, int out_size, void* d_ws, size_t ws_size,
                              hipStream_t stream)
{
    constexpr int N = NN, E = EE, G = GG;
    constexpr int ND = N * 64;

    const void* x     = d_in[0];
    const void* W1    = d_in[1];
    const void* b1    = d_in[2];
    const void* W2    = d_in[3];
    const void* b2    = d_in[4];
    const void* gamma = d_in[5];
    const void* beta  = d_in[6];
    const int* ei     = (const int*)d_in[7];
    const int* batw   = (const int*)d_in[8];

    char* p = (char*)d_ws;
    auto alloc = [&](size_t bytes) -> char* {
        char* r = p;
        p += (bytes + 255) & ~(size_t)255;
        return r;
    };
    float*    hf        = (float*)alloc((size_t)ND * 4);
    float*    zf        = (float*)alloc((size_t)ND * 4);
    float*    node_pool = (float*)alloc((size_t)ND * 4);
    ushort_t* hb        = (ushort_t*)alloc((size_t)ND * 2);
    int*      esrc      = (int*)alloc((size_t)E * 4);
    int*      indptr    = (int*)alloc((size_t)(N + 1) * 4);
    int*      deg       = (int*)alloc((size_t)N * 4);
    int*      part      = (int*)alloc((size_t)N * 4);
    float*    invdeg    = (float*)alloc((size_t)N * 4);
    int*      b32       = (int*)alloc((size_t)N * 4);
    int*      bsum      = (int*)alloc(128 * 4);
    int*      gcnt      = (int*)alloc(G * 4);
    float*    invg      = (float*)alloc(G * 4);
    float*    gpool     = (float*)alloc((size_t)G * 64 * 4);
    float*    stats     = (float*)alloc(128 * 4);
    float*    ac        = (float*)alloc(128 * 4);
    float*    wf        = (float*)alloc(33792 * 4);
    int*      flags     = (int*)alloc(16 * 4);
    int*      histo     = (int*)alloc((size_t)NBK * NHB * 4);
    int*      tot       = (int*)alloc((size_t)NBK * 4);
    int*      bktoff    = (int*)alloc((size_t)(NBK + 1) * 4);
    // pairs aliases node_pool: dead until first bn_pool; E*8 == ND*4 bytes
    int2*     pairs     = (int2*)node_pool;

    hipMemsetAsync(gcnt,  0, (size_t)G * 4,      stream);
    hipMemsetAsync(gpool, 0, (size_t)G * 64 * 4, stream);

    detect_kernel<<<1, 256, 0, stream>>>(
        (const uint_t*)x, (const uint_t*)ei, (const uint_t*)batw, flags);
    cvt_w_kernel<<<132, 256, 0, stream>>>(W1, b1, W2, b2, gamma, beta, flags, wf);
    cvt_x_kernel<<<(ND + 255) / 256, 256, 0, stream>>>(x, flags, hf, hb, ND);
    cvt_batch_kernel<<<(N + 255) / 256, 256, 0, stream>>>(batw, flags, b32, gcnt, N);
    count_hist_kernel<<<NHB, 256, 0, stream>>>(ei, flags, histo, E);
    blockscan_kernel<<<NBK, NHB, 0, stream>>>(histo, tot);
    bscan_kernel<<<1, 512, 0, stream>>>(tot, bktoff);
    pair_scatter_kernel<<<NHB, 256, 0, stream>>>(ei, flags, histo, bktoff, pairs, E);
    bucket_deg_kernel<<<NBK, 256, 0, stream>>>(pairs, bktoff, deg, N);
    int nb = (N + 1023) / 1024;  // 98
    scan1_kernel<<<nb, 256, 0, stream>>>(deg, part, bsum, N);
    scan2_kernel<<<1, 128, 0, stream>>>(bsum, nb);
    scan3_kernel<<<(N + 255) / 256, 256, 0, stream>>>(part, bsum, deg, indptr, invdeg, N);
    invg_kernel<<<1, 512, 0, stream>>>(gcnt, invg, G);
    csr_fill_kernel<<<NBK, 256, 0, stream>>>(pairs, bktoff, indptr, esrc, N);

    for (int l = 0; l < 4; ++l) {
        agg_kernel<<<(N + 15) / 16, 256, 0, stream>>>(
            hf, hb, indptr, esrc, invdeg, zf, N);
        mlp_kernel<<<(N + 255) / 256, 256, 0, stream>>>(
            zf, wf + l * 4096, wf + 32768 + l * 64,
            wf + 16384 + l * 4096, wf + 33024 + l * 64, N);
        hipMemsetAsync(stats, 0, 128 * 4, stream);
        stats_kernel<<<256, 256, 0, stream>>>(zf, stats, N);
        bnfin_kernel<<<1, 64, 0, stream>>>(
            stats, wf + 33280 + l * 64, wf + 33536 + l * 64, ac, N);
        bn_pool_kernel<<<(N + 255) / 256, 256, 0, stream>>>(
            zf, hf, hb, node_pool, b32, ac, gpool, N, (l == 0) ? 1 : 0);
    }
    finalize_kernel<<<(ND + G * 64 + 255) / 256, 256, 0, stream>>>(
        node_pool, gpool, invg, flags, d_out, N);
}

// Round 10
// 1129.479 us; speedup vs baseline: 1.5000x; 1.1007x over previous
//
#include <hip/hip_runtime.h>
#include <hip/hip_bf16.h>

// GIN_34789235098229 — round 10: agg MLP-boost + BN-affine folding.
// Round 9 = 1243 us; top = agg 106us x4: FETCH 170MB vs 410MB gather volume,
// VALU 18%, occ 66% -> latency-bound, ~1 outstanding gather/lane + 16x
// redundant esrc loads. Fixes:
//  (1) agg: 16-lane group loads 16 edge ids coalesced, __shfl-broadcasts,
//      issues 16 independent row gathers (unrolled) -> high MLP.
//  (2) BN folded as affine into agg/pool: carry only pre-BN z (fp32 ping-pong
//      + bf16 mirror written by mlp epilogue). z_in_next =
//      A*(z_own + mean(z_nb)) + C*(1+[deg>0]); pools use h = A*z + C.
//      Deletes h(25.6MB)+hb(12.8MB) writes per layer. ac = identity at l=0.
// Build (atomic-free, r9) and mlp/stats numerics unchanged.

typedef unsigned short ushort_t;
typedef unsigned int uint_t;

#define NN 100000
#define EE 3200000
#define GG 512
#define NBK 391    // ceil(NN/256); bucket = node >> 8
#define NHB 256    // histogram blocks
#define ECHUNK 12500  // EE / NHB exactly

// ---------- detection ----------
__global__ __launch_bounds__(256) void detect_kernel(
    const uint_t* __restrict__ xw, const uint_t* __restrict__ ew,
    const uint_t* __restrict__ bw, int* __restrict__ flags)
{
    __shared__ int sb[256], se[256], sbb[256];
    int t = threadIdx.x;
    uint_t w = xw[t];
    uint_t eL = (w >> 7) & 0xffu;
    sb[t] = (eL >= 112u && eL <= 135u) ? 1 : 0;
    se[t] = (ew[2 * t + 1] == 0u) ? 1 : 0;
    sbb[t] = (bw[NN - 512 + 2 * t + 1] == 0u) ? 1 : 0;
    __syncthreads();
    for (int off = 128; off > 0; off >>= 1) {
        if (t < off) { sb[t] += sb[t + off]; se[t] += se[t + off]; sbb[t] += sbb[t + off]; }
        __syncthreads();
    }
    if (t == 0) {
        flags[0] = (sb[0] < 128) ? 1 : 0;   // 1 => fp32 floats
        flags[1] = (se[0] >= 128) ? 1 : 0;  // 1 => int64 edges
        flags[2] = (sbb[0] >= 128) ? 1 : 0; // 1 => int64 batch
    }
}

// ---------- canonicalization ----------
__global__ __launch_bounds__(256) void cvt_w_kernel(
    const void* __restrict__ W1, const void* __restrict__ b1,
    const void* __restrict__ W2, const void* __restrict__ b2,
    const void* __restrict__ g, const void* __restrict__ be,
    const int* __restrict__ flags, float* __restrict__ wf)
{
    int i = blockIdx.x * 256 + threadIdx.x;
    if (i >= 33792) return;
    const void* src; int off;
    if (i < 16384)      { src = W1; off = i; }
    else if (i < 32768) { src = W2; off = i - 16384; }
    else if (i < 33024) { src = b1; off = i - 32768; }
    else if (i < 33280) { src = b2; off = i - 33024; }
    else if (i < 33536) { src = g;  off = i - 33280; }
    else                { src = be; off = i - 33536; }
    float v = flags[0] ? ((const float*)src)[off]
                       : __bfloat162float(((const __hip_bfloat16*)src)[off]);
    wf[i] = v;
}

__global__ __launch_bounds__(256) void cvt_x_kernel(
    const void* __restrict__ x, const int* __restrict__ flags,
    float* __restrict__ zA, ushort_t* __restrict__ zb, int total)
{
    int i = blockIdx.x * 256 + threadIdx.x;
    if (i >= total) return;
    float v;
    ushort_t bits;
    if (flags[0]) {
        v = ((const float*)x)[i];
        __hip_bfloat16 b = __float2bfloat16(v);
        bits = *(ushort_t*)&b;
    } else {
        bits = ((const ushort_t*)x)[i];
        uint_t u = (uint_t)bits << 16;
        v = __uint_as_float(u);
    }
    zA[i] = v;
    zb[i] = bits;
}

__global__ __launch_bounds__(256) void cvt_batch_kernel(
    const int* __restrict__ bw, const int* __restrict__ flags,
    int* __restrict__ b32, int* __restrict__ gcnt, int n)
{
    int i = blockIdx.x * 256 + threadIdx.x;
    if (i >= n) return;
    int v = flags[2] ? bw[2 * i] : bw[i];
    b32[i] = v;
    atomicAdd(&gcnt[v], 1);
}

// ---------- atomic-free CSR build (round 9, unchanged) ----------
__global__ __launch_bounds__(256) void count_hist_kernel(
    const int* __restrict__ ei, const int* __restrict__ flags,
    int* __restrict__ histo, int E)
{
    __shared__ int lh[NBK];
    int b = blockIdx.x, t = threadIdx.x;
    for (int j = t; j < NBK; j += 256) lh[j] = 0;
    __syncthreads();
    int i64 = flags[1];
    int e0 = b * ECHUNK, e1 = min(e0 + ECHUNK, E);
    for (int i = e0 + t; i < e1; i += 256) {
        int d = i64 ? ei[2 * (E + i)] : ei[E + i];
        atomicAdd(&lh[d >> 8], 1);
    }
    __syncthreads();
    for (int j = t; j < NBK; j += 256) histo[j * NHB + b] = lh[j];
}

__global__ __launch_bounds__(NHB) void blockscan_kernel(
    int* __restrict__ histo, int* __restrict__ tot)
{
    __shared__ int sd[NHB];
    int j = blockIdx.x, t = threadIdx.x;
    int v = histo[j * NHB + t];
    sd[t] = v;
    __syncthreads();
    #pragma unroll
    for (int off = 1; off < NHB; off <<= 1) {
        int add = (t >= off) ? sd[t - off] : 0;
        __syncthreads();
        sd[t] += add;
        __syncthreads();
    }
    histo[j * NHB + t] = sd[t] - v;
    if (t == NHB - 1) tot[j] = sd[NHB - 1];
}

__global__ __launch_bounds__(512) void bscan_kernel(
    const int* __restrict__ tot, int* __restrict__ bktoff)
{
    __shared__ int sd[512];
    int t = threadIdx.x;
    int v = (t < NBK) ? tot[t] : 0;
    sd[t] = v;
    __syncthreads();
    #pragma unroll
    for (int off = 1; off < 512; off <<= 1) {
        int add = (t >= off) ? sd[t - off] : 0;
        __syncthreads();
        sd[t] += add;
        __syncthreads();
    }
    if (t < NBK) bktoff[t] = sd[t] - v;
    if (t == 511) bktoff[NBK] = sd[511];
}

__global__ __launch_bounds__(256) void pair_scatter_kernel(
    const int* __restrict__ ei, const int* __restrict__ flags,
    const int* __restrict__ histo, const int* __restrict__ bktoff,
    int2* __restrict__ pairs, int E)
{
    __shared__ int cur[NBK];
    int b = blockIdx.x, t = threadIdx.x;
    for (int j = t; j < NBK; j += 256) cur[j] = histo[j * NHB + b] + bktoff[j];
    __syncthreads();
    int i64 = flags[1];
    int e0 = b * ECHUNK, e1 = min(e0 + ECHUNK, E);
    for (int i = e0 + t; i < e1; i += 256) {
        int d = i64 ? ei[2 * (E + i)] : ei[E + i];
        int s = i64 ? ei[2 * i]       : ei[i];
        int p = atomicAdd(&cur[d >> 8], 1);
        pairs[p] = make_int2(d, s);
    }
}

__global__ __launch_bounds__(256) void bucket_deg_kernel(
    const int2* __restrict__ pairs, const int* __restrict__ bktoff,
    int* __restrict__ deg, int N)
{
    __shared__ int cnt[256];
    int j = blockIdx.x, t = threadIdx.x;
    cnt[t] = 0;
    __syncthreads();
    int e0 = bktoff[j], e1 = bktoff[j + 1];
    for (int i = e0 + t; i < e1; i += 256)
        atomicAdd(&cnt[pairs[i].x & 255], 1);
    __syncthreads();
    int idx = j * 256 + t;
    if (idx < N) deg[idx] = cnt[t];
}

__global__ __launch_bounds__(256) void scan1_kernel(
    const int* __restrict__ deg, int* __restrict__ part, int* __restrict__ bsum, int n)
{
    __shared__ int sd[256];
    int t = threadIdx.x;
    int i0 = blockIdx.x * 1024 + t * 4;
    int v0 = 0, v1 = 0, v2 = 0, v3 = 0;
    if (i0 + 3 < n) {
        int4 v = *(const int4*)(deg + i0);
        v0 = v.x; v1 = v.y; v2 = v.z; v3 = v.w;
    } else if (i0 < n) {
        v0 = deg[i0];
        if (i0 + 1 < n) v1 = deg[i0 + 1];
        if (i0 + 2 < n) v2 = deg[i0 + 2];
    }
    int s = v0 + v1 + v2 + v3;
    sd[t] = s;
    __syncthreads();
    #pragma unroll
    for (int off = 1; off < 256; off <<= 1) {
        int add = (t >= off) ? sd[t - off] : 0;
        __syncthreads();
        sd[t] += add;
        __syncthreads();
    }
    int incl = sd[t];
    int e0 = incl - s;
    int p0 = e0 + v0, p1 = p0 + v1, p2 = p1 + v2, p3 = p2 + v3;
    if (i0 < n)     part[i0]     = p0;
    if (i0 + 1 < n) part[i0 + 1] = p1;
    if (i0 + 2 < n) part[i0 + 2] = p2;
    if (i0 + 3 < n) part[i0 + 3] = p3;
    if (t == 255) bsum[blockIdx.x] = incl;
}

__global__ __launch_bounds__(128) void scan2_kernel(int* __restrict__ bsum, int nb)
{
    __shared__ int sd[128];
    int t = threadIdx.x;
    int own = (t < nb) ? bsum[t] : 0;
    sd[t] = own;
    __syncthreads();
    #pragma unroll
    for (int off = 1; off < 128; off <<= 1) {
        int add = (t >= off) ? sd[t - off] : 0;
        __syncthreads();
        sd[t] += add;
        __syncthreads();
    }
    if (t < nb) bsum[t] = sd[t] - own;
}

__global__ __launch_bounds__(256) void scan3_kernel(
    const int* __restrict__ part, const int* __restrict__ bsum,
    const int* __restrict__ deg, int* __restrict__ indptr,
    float* __restrict__ inv_deg, int n)
{
    int i = blockIdx.x * 256 + threadIdx.x;
    if (i >= n) return;
    int val = part[i] + bsum[i >> 10];
    indptr[i + 1] = val;
    int d = deg[i];
    inv_deg[i] = (d > 0) ? 1.0f / (float)d : 0.0f;
    if (i == 0) indptr[0] = 0;
}

// invg + identity-init of the BN affine (A=1, C=0) for layer 0's agg
__global__ __launch_bounds__(512) void invg_kernel(
    const int* __restrict__ gcnt, float* __restrict__ invg,
    float* __restrict__ ac, int G)
{
    int g = threadIdx.x;
    if (g < G) {
        int c = gcnt[g];
        invg[g] = (c > 0) ? 1.0f / (float)c : 0.0f;
    }
    if (g < 64) ac[g] = 1.0f;
    else if (g < 128) ac[g] = 0.0f;
}

__global__ __launch_bounds__(256) void csr_fill_kernel(
    const int2* __restrict__ pairs, const int* __restrict__ bktoff,
    const int* __restrict__ indptr, int* __restrict__ esrc, int N)
{
    __shared__ int cur[256];
    int j = blockIdx.x, t = threadIdx.x;
    int idx = j * 256 + t;
    cur[t] = (idx < N) ? indptr[idx] : 0;
    __syncthreads();
    int e0 = bktoff[j], e1 = bktoff[j + 1];
    for (int i = e0 + t; i < e1; i += 256) {
        int2 e = pairs[i];
        int p = atomicAdd(&cur[e.x & 255], 1);
        esrc[p] = e.y;
    }
}

// ---------- per-layer ----------
// agg with edge-index broadcast + unrolled independent gathers.
// zout = A*(z_own + mean(z_nb)) + C*(1+[deg>0])   (BN affine of PREVIOUS layer)
__global__ __launch_bounds__(256) void agg_kernel(
    const float* __restrict__ zprev, const ushort_t* __restrict__ zb,
    const int* __restrict__ indptr, const int* __restrict__ esrc,
    const float* __restrict__ inv_deg, const float* __restrict__ ac,
    float* __restrict__ zout, int n)
{
    int t = threadIdx.x;
    int grp = t >> 4, l = t & 15;
    int lane = t & 63;
    int gl0 = lane & 48;           // first wave-lane of my 16-lane group
    int node = blockIdx.x * 16 + grp;
    if (node >= n) return;
    int e0 = indptr[node], e1 = indptr[node + 1];
    float a0 = 0.f, a1 = 0.f, a2 = 0.f, a3 = 0.f;
    const ushort_t* zbl = zb + l * 4;
    for (int base = e0; base < e1; base += 16) {
        int cnt = e1 - base;
        if (cnt > 16) cnt = 16;
        int myi = (l < cnt) ? esrc[base + l] : 0;  // 16 coalesced 4B loads
        if (cnt == 16) {
            #pragma unroll
            for (int j = 0; j < 16; ++j) {
                int s = __shfl(myi, gl0 + j, 64);
                uint2 v = *(const uint2*)(zbl + (size_t)s * 64);
                a0 += __uint_as_float(v.x << 16);
                a1 += __uint_as_float(v.x & 0xffff0000u);
                a2 += __uint_as_float(v.y << 16);
                a3 += __uint_as_float(v.y & 0xffff0000u);
            }
        } else {
            for (int j = 0; j < cnt; ++j) {
                int s = __shfl(myi, gl0 + j, 64);
                uint2 v = *(const uint2*)(zbl + (size_t)s * 64);
                a0 += __uint_as_float(v.x << 16);
                a1 += __uint_as_float(v.x & 0xffff0000u);
                a2 += __uint_as_float(v.y << 16);
                a3 += __uint_as_float(v.y & 0xffff0000u);
            }
        }
    }
    float idg = inv_deg[node];
    float cf = (idg > 0.f) ? 2.f : 1.f;
    float4 own = *(const float4*)(zprev + (size_t)node * 64 + l * 4);
    float4 A = *(const float4*)(ac + l * 4);
    float4 C = *(const float4*)(ac + 64 + l * 4);
    float4 r;
    r.x = fmaf(A.x, fmaf(idg, a0, own.x), C.x * cf);
    r.y = fmaf(A.y, fmaf(idg, a1, own.y), C.y * cf);
    r.z = fmaf(A.z, fmaf(idg, a2, own.z), C.z * cf);
    r.w = fmaf(A.w, fmaf(idg, a3, own.w), C.w * cf);
    *(float4*)(zout + (size_t)node * 64 + l * 4) = r;
}

// z <- relu(relu(z@W1+b1)@W2+b2) in place + bf16 mirror write; spill-free.
__global__ __launch_bounds__(256, 2) void mlp_kernel(
    float* __restrict__ zf, ushort_t* __restrict__ zb,
    const float* __restrict__ W1f, const float* __restrict__ b1f,
    const float* __restrict__ W2f, const float* __restrict__ b2f,
    int n)
{
    __shared__ float w1s[4096];
    __shared__ float w2s[4096];
    __shared__ float bs[128];
    int t = threadIdx.x;
    for (int i = t; i < 4096; i += 256) {
        w1s[i] = W1f[i];
        w2s[i] = W2f[i];
    }
    if (t < 64) bs[t] = b1f[t];
    else if (t < 128) bs[t] = b2f[t - 64];
    __syncthreads();

    int node = blockIdx.x * 256 + t;
    if (node >= n) return;
    float* zrow = zf + (size_t)node * 64;
    ushort_t* zbrow = zb + (size_t)node * 64;

    float y[64];
    #pragma unroll
    for (int j = 0; j < 64; ++j) y[j] = bs[j];
    #pragma unroll
    for (int kb = 0; kb < 4; ++kb) {
        float4 c0 = *(const float4*)(zrow + kb * 16);
        float4 c1 = *(const float4*)(zrow + kb * 16 + 4);
        float4 c2 = *(const float4*)(zrow + kb * 16 + 8);
        float4 c3 = *(const float4*)(zrow + kb * 16 + 12);
        float zc[16] = {c0.x, c0.y, c0.z, c0.w, c1.x, c1.y, c1.z, c1.w,
                        c2.x, c2.y, c2.z, c2.w, c3.x, c3.y, c3.z, c3.w};
        #pragma unroll
        for (int k = 0; k < 16; ++k) {
            float a = zc[k];
            const float4* w = (const float4*)(w1s + (kb * 16 + k) * 64);
            #pragma unroll
            for (int q = 0; q < 16; ++q) {
                float4 wv = w[q];
                y[4*q]   = fmaf(a, wv.x, y[4*q]);
                y[4*q+1] = fmaf(a, wv.y, y[4*q+1]);
                y[4*q+2] = fmaf(a, wv.z, y[4*q+2]);
                y[4*q+3] = fmaf(a, wv.w, y[4*q+3]);
            }
        }
    }
    #pragma unroll
    for (int j = 0; j < 64; ++j) y[j] = fmaxf(y[j], 0.f);

    #pragma unroll
    for (int jb = 0; jb < 4; ++jb) {
        float o[16];
        #pragma unroll
        for (int q = 0; q < 16; ++q) o[q] = bs[64 + jb * 16 + q];
        #pragma unroll
        for (int k = 0; k < 64; ++k) {
            float a = y[k];
            const float4* w = (const float4*)(w2s + k * 64 + jb * 16);
            #pragma unroll
            for (int q = 0; q < 4; ++q) {
                float4 wv = w[q];
                o[4*q]   = fmaf(a, wv.x, o[4*q]);
                o[4*q+1] = fmaf(a, wv.y, o[4*q+1]);
                o[4*q+2] = fmaf(a, wv.z, o[4*q+2]);
                o[4*q+3] = fmaf(a, wv.w, o[4*q+3]);
            }
        }
        #pragma unroll
        for (int q = 0; q < 4; ++q) {
            float4 v;
            v.x = fmaxf(o[4*q],   0.f);
            v.y = fmaxf(o[4*q+1], 0.f);
            v.z = fmaxf(o[4*q+2], 0.f);
            v.w = fmaxf(o[4*q+3], 0.f);
            *(float4*)(zrow + jb * 16 + q * 4) = v;
            __hip_bfloat16 p0 = __float2bfloat16(v.x);
            __hip_bfloat16 p1 = __float2bfloat16(v.y);
            __hip_bfloat16 p2 = __float2bfloat16(v.z);
            __hip_bfloat16 p3 = __float2bfloat16(v.w);
            uint2 pw;
            pw.x = (uint_t)*(ushort_t*)&p0 | ((uint_t)*(ushort_t*)&p1 << 16);
            pw.y = (uint_t)*(ushort_t*)&p2 | ((uint_t)*(ushort_t*)&p3 << 16);
            *(uint2*)(zbrow + jb * 16 + q * 4) = pw;
        }
    }
}

// per-feature sum / sumsq -> float atomics (128 addresses)
__global__ __launch_bounds__(256) void stats_kernel(
    const float* __restrict__ z, float* __restrict__ stats, int N)
{
    __shared__ float ssum[256], ssq[256];
    int t = threadIdx.x;
    float s = 0.f, q = 0.f;
    int total = N * 64;
    for (int i = blockIdx.x * 256 + t; i < total; i += 256 * gridDim.x) {
        float v = z[i];
        s += v;
        q += v * v;
    }
    ssum[t] = s; ssq[t] = q;
    __syncthreads();
    if (t < 64) {
        float S = ssum[t] + ssum[t+64] + ssum[t+128] + ssum[t+192];
        float Q = ssq[t]  + ssq[t+64]  + ssq[t+128]  + ssq[t+192];
        atomicAdd(&stats[t], S);
        atomicAdd(&stats[64 + t], Q);
    }
}

__global__ __launch_bounds__(64) void bnfin_kernel(
    const float* __restrict__ stats, const float* __restrict__ gammaf,
    const float* __restrict__ betaf, float* __restrict__ ac, int N)
{
    int f = threadIdx.x;
    if (f >= 64) return;
    float invN = 1.0f / (float)N;
    float mu = stats[f] * invN;
    float var = stats[64 + f] * invN - mu * mu;
    if (var < 0.f) var = 0.f;
    float inv = rsqrtf(var + 1e-5f);
    float A = gammaf[f] * inv;
    float C = betaf[f] - mu * A;
    ac[f] = A;
    ac[64 + f] = C;
}

// pools only: h = A*z + C on the fly; node_pool (+=), gpool run-length atomics
__global__ __launch_bounds__(256) void pool_kernel(
    const float* __restrict__ z, float* __restrict__ node_pool,
    const int* __restrict__ b32, const float* __restrict__ ac,
    float* __restrict__ gpool, int N, int first)
{
    int wave = (blockIdx.x * 256 + threadIdx.x) >> 6;
    int f = threadIdx.x & 63;
    int n0 = wave * 64;
    if (n0 >= N) return;
    int n1 = min(n0 + 64, N);
    float A = ac[f], C = ac[64 + f];
    float racc = 0.f;
    int cur = b32[n0];
    for (int n = n0; n < n1; ++n) {
        int g = b32[n];
        if (g != cur) {  // wave-uniform branch
            atomicAdd(&gpool[(size_t)cur * 64 + f], racc);
            racc = 0.f;
            cur = g;
        }
        size_t idx = (size_t)n * 64 + f;
        float hv = fmaf(z[idx], A, C);
        float np = first ? hv : (node_pool[idx] + hv);
        node_pool[idx] = np;
        racc += hv;
    }
    atomicAdd(&gpool[(size_t)cur * 64 + f], racc);
}

__global__ __launch_bounds__(256) void finalize_kernel(
    const float* __restrict__ node_pool, const float* __restrict__ gpool,
    const float* __restrict__ invg, const int* __restrict__ flags,
    void* __restrict__ out, int N)
{
    int i = blockIdx.x * 256 + threadIdx.x;
    int nd = N * 64;
    int total = nd + GG * 64;
    if (i >= total) return;
    float v;
    if (i < nd) v = node_pool[i];
    else { int j = i - nd; v = gpool[j] * invg[j >> 6]; }
    if (flags[0]) ((float*)out)[i] = v;
    else ((__hip_bfloat16*)out)[i] = __float2bfloat16(v);
}

extern "C" void kernel_launch(void* const* d_in, const int* in_sizes, int n_in,
                              void* d_out, int out_size, void* d_ws, size_t ws_size,
                              hipStream_t stream)
{
    constexpr int N = NN, E = EE, G = GG;
    constexpr int ND = N * 64;

    const void* x     = d_in[0];
    const void* W1    = d_in[1];
    const void* b1    = d_in[2];
    const void* W2    = d_in[3];
    const void* b2    = d_in[4];
    const void* gamma = d_in[5];
    const void* beta  = d_in[6];
    const int* ei     = (const int*)d_in[7];
    const int* batw   = (const int*)d_in[8];

    char* p = (char*)d_ws;
    auto alloc = [&](size_t bytes) -> char* {
        char* r = p;
        p += (bytes + 255) & ~(size_t)255;
        return r;
    };
    float*    zbufA     = (float*)alloc((size_t)ND * 4);
    float*    zbufB     = (float*)alloc((size_t)ND * 4);
    float*    node_pool = (float*)alloc((size_t)ND * 4);
    ushort_t* zb        = (ushort_t*)alloc((size_t)ND * 2);
    int*      esrc      = (int*)alloc((size_t)E * 4);
    int*      indptr    = (int*)alloc((size_t)(N + 1) * 4);
    int*      deg       = (int*)alloc((size_t)N * 4);
    int*      part      = (int*)alloc((size_t)N * 4);
    float*    invdeg    = (float*)alloc((size_t)N * 4);
    int*      b32       = (int*)alloc((size_t)N * 4);
    int*      bsum      = (int*)alloc(128 * 4);
    int*      gcnt      = (int*)alloc(G * 4);
    float*    invg      = (float*)alloc(G * 4);
    float*    gpool     = (float*)alloc((size_t)G * 64 * 4);
    float*    stats     = (float*)alloc(128 * 4);
    float*    ac        = (float*)alloc(128 * 4);
    float*    wf        = (float*)alloc(33792 * 4);
    int*      flags     = (int*)alloc(16 * 4);
    int*      histo     = (int*)alloc((size_t)NBK * NHB * 4);
    int*      tot       = (int*)alloc((size_t)NBK * 4);
    int*      bktoff    = (int*)alloc((size_t)(NBK + 1) * 4);
    // pairs aliases node_pool: dead until first pool_kernel; E*8 == ND*4 bytes
    int2*     pairs     = (int2*)node_pool;

    hipMemsetAsync(gcnt,  0, (size_t)G * 4,      stream);
    hipMemsetAsync(gpool, 0, (size_t)G * 64 * 4, stream);

    detect_kernel<<<1, 256, 0, stream>>>(
        (const uint_t*)x, (const uint_t*)ei, (const uint_t*)batw, flags);
    cvt_w_kernel<<<132, 256, 0, stream>>>(W1, b1, W2, b2, gamma, beta, flags, wf);
    cvt_x_kernel<<<(ND + 255) / 256, 256, 0, stream>>>(x, flags, zbufA, zb, ND);
    cvt_batch_kernel<<<(N + 255) / 256, 256, 0, stream>>>(batw, flags, b32, gcnt, N);
    count_hist_kernel<<<NHB, 256, 0, stream>>>(ei, flags, histo, E);
    blockscan_kernel<<<NBK, NHB, 0, stream>>>(histo, tot);
    bscan_kernel<<<1, 512, 0, stream>>>(tot, bktoff);
    pair_scatter_kernel<<<NHB, 256, 0, stream>>>(ei, flags, histo, bktoff, pairs, E);
    bucket_deg_kernel<<<NBK, 256, 0, stream>>>(pairs, bktoff, deg, N);
    int nb = (N + 1023) / 1024;  // 98
    scan1_kernel<<<nb, 256, 0, stream>>>(deg, part, bsum, N);
    scan2_kernel<<<1, 128, 0, stream>>>(bsum, nb);
    scan3_kernel<<<(N + 255) / 256, 256, 0, stream>>>(part, bsum, deg, indptr, invdeg, N);
    invg_kernel<<<1, 512, 0, stream>>>(gcnt, invg, ac, G);
    csr_fill_kernel<<<NBK, 256, 0, stream>>>(pairs, bktoff, indptr, esrc, N);

    float* zin = zbufA;
    float* zout = zbufB;
    for (int l = 0; l < 4; ++l) {
        agg_kernel<<<(N + 15) / 16, 256, 0, stream>>>(
            zin, zb, indptr, esrc, invdeg, ac, zout, N);
        mlp_kernel<<<(N + 255) / 256, 256, 0, stream>>>(
            zout, zb, wf + l * 4096, wf + 32768 + l * 64,
            wf + 16384 + l * 4096, wf + 33024 + l * 64, N);
        hipMemsetAsync(stats, 0, 128 * 4, stream);
        stats_kernel<<<256, 256, 0, stream>>>(zout, stats, N);
        bnfin_kernel<<<1, 64, 0, stream>>>(
            stats, wf + 33280 + l * 64, wf + 33536 + l * 64, ac, N);
        pool_kernel<<<(N + 255) / 256, 256, 0, stream>>>(
            zout, node_pool, b32, ac, gpool, N, (l == 0) ? 1 : 0);
        float* tmp = zin; zin = zout; zout = tmp;
    }
    finalize_kernel<<<(ND + G * 64 + 255) / 256, 256, 0, stream>>>(
        node_pool, gpool, invg, flags, d_out, N);
}

// Round 11
// 1079.902 us; speedup vs baseline: 1.5688x; 1.0459x over previous
//
#include <hip/hip_runtime.h>
#include <hip/hip_bf16.h>

// GIN_34789235098229 — round 11: MLP re-parallelized 4 lanes/node.
// Round 10 = 1129 us; top = mlp 157us x4 with Occupancy 17.7%, VALU 10%:
// thread-per-node => grid 391 blocks => ~1.5 blocks/CU. Parallelism-starved,
// not compute-bound. Fix: 4 lanes per node, each owns a 16-feature slice;
// shared GEMM operands broadcast via __shfl within the 4-lane group
// (128 shuffles vs 2048 FMAs); LDS weight reads are 16-way broadcasts (free).
// Grid 1563 blocks -> 4 blocks/CU (LDS-capped) = 50% occupancy. Stores are
// group-contiguous (kills r10's 2x write amplification). Same FMA order ->
// bit-identical numerics. Everything else unchanged from round 10.

typedef unsigned short ushort_t;
typedef unsigned int uint_t;

#define NN 100000
#define EE 3200000
#define GG 512
#define NBK 391    // ceil(NN/256); bucket = node >> 8
#define NHB 256    // histogram blocks
#define ECHUNK 12500  // EE / NHB exactly

// ---------- detection ----------
__global__ __launch_bounds__(256) void detect_kernel(
    const uint_t* __restrict__ xw, const uint_t* __restrict__ ew,
    const uint_t* __restrict__ bw, int* __restrict__ flags)
{
    __shared__ int sb[256], se[256], sbb[256];
    int t = threadIdx.x;
    uint_t w = xw[t];
    uint_t eL = (w >> 7) & 0xffu;
    sb[t] = (eL >= 112u && eL <= 135u) ? 1 : 0;
    se[t] = (ew[2 * t + 1] == 0u) ? 1 : 0;
    sbb[t] = (bw[NN - 512 + 2 * t + 1] == 0u) ? 1 : 0;
    __syncthreads();
    for (int off = 128; off > 0; off >>= 1) {
        if (t < off) { sb[t] += sb[t + off]; se[t] += se[t + off]; sbb[t] += sbb[t + off]; }
        __syncthreads();
    }
    if (t == 0) {
        flags[0] = (sb[0] < 128) ? 1 : 0;   // 1 => fp32 floats
        flags[1] = (se[0] >= 128) ? 1 : 0;  // 1 => int64 edges
        flags[2] = (sbb[0] >= 128) ? 1 : 0; // 1 => int64 batch
    }
}

// ---------- canonicalization ----------
__global__ __launch_bounds__(256) void cvt_w_kernel(
    const void* __restrict__ W1, const void* __restrict__ b1,
    const void* __restrict__ W2, const void* __restrict__ b2,
    const void* __restrict__ g, const void* __restrict__ be,
    const int* __restrict__ flags, float* __restrict__ wf)
{
    int i = blockIdx.x * 256 + threadIdx.x;
    if (i >= 33792) return;
    const void* src; int off;
    if (i < 16384)      { src = W1; off = i; }
    else if (i < 32768) { src = W2; off = i - 16384; }
    else if (i < 33024) { src = b1; off = i - 32768; }
    else if (i < 33280) { src = b2; off = i - 33024; }
    else if (i < 33536) { src = g;  off = i - 33280; }
    else                { src = be; off = i - 33536; }
    float v = flags[0] ? ((const float*)src)[off]
                       : __bfloat162float(((const __hip_bfloat16*)src)[off]);
    wf[i] = v;
}

__global__ __launch_bounds__(256) void cvt_x_kernel(
    const void* __restrict__ x, const int* __restrict__ flags,
    float* __restrict__ zA, ushort_t* __restrict__ zb, int total)
{
    int i = blockIdx.x * 256 + threadIdx.x;
    if (i >= total) return;
    float v;
    ushort_t bits;
    if (flags[0]) {
        v = ((const float*)x)[i];
        __hip_bfloat16 b = __float2bfloat16(v);
        bits = *(ushort_t*)&b;
    } else {
        bits = ((const ushort_t*)x)[i];
        uint_t u = (uint_t)bits << 16;
        v = __uint_as_float(u);
    }
    zA[i] = v;
    zb[i] = bits;
}

__global__ __launch_bounds__(256) void cvt_batch_kernel(
    const int* __restrict__ bw, const int* __restrict__ flags,
    int* __restrict__ b32, int* __restrict__ gcnt, int n)
{
    int i = blockIdx.x * 256 + threadIdx.x;
    if (i >= n) return;
    int v = flags[2] ? bw[2 * i] : bw[i];
    b32[i] = v;
    atomicAdd(&gcnt[v], 1);
}

// ---------- atomic-free CSR build (round 9, unchanged) ----------
__global__ __launch_bounds__(256) void count_hist_kernel(
    const int* __restrict__ ei, const int* __restrict__ flags,
    int* __restrict__ histo, int E)
{
    __shared__ int lh[NBK];
    int b = blockIdx.x, t = threadIdx.x;
    for (int j = t; j < NBK; j += 256) lh[j] = 0;
    __syncthreads();
    int i64 = flags[1];
    int e0 = b * ECHUNK, e1 = min(e0 + ECHUNK, E);
    for (int i = e0 + t; i < e1; i += 256) {
        int d = i64 ? ei[2 * (E + i)] : ei[E + i];
        atomicAdd(&lh[d >> 8], 1);
    }
    __syncthreads();
    for (int j = t; j < NBK; j += 256) histo[j * NHB + b] = lh[j];
}

__global__ __launch_bounds__(NHB) void blockscan_kernel(
    int* __restrict__ histo, int* __restrict__ tot)
{
    __shared__ int sd[NHB];
    int j = blockIdx.x, t = threadIdx.x;
    int v = histo[j * NHB + t];
    sd[t] = v;
    __syncthreads();
    #pragma unroll
    for (int off = 1; off < NHB; off <<= 1) {
        int add = (t >= off) ? sd[t - off] : 0;
        __syncthreads();
        sd[t] += add;
        __syncthreads();
    }
    histo[j * NHB + t] = sd[t] - v;
    if (t == NHB - 1) tot[j] = sd[NHB - 1];
}

__global__ __launch_bounds__(512) void bscan_kernel(
    const int* __restrict__ tot, int* __restrict__ bktoff)
{
    __shared__ int sd[512];
    int t = threadIdx.x;
    int v = (t < NBK) ? tot[t] : 0;
    sd[t] = v;
    __syncthreads();
    #pragma unroll
    for (int off = 1; off < 512; off <<= 1) {
        int add = (t >= off) ? sd[t - off] : 0;
        __syncthreads();
        sd[t] += add;
        __syncthreads();
    }
    if (t < NBK) bktoff[t] = sd[t] - v;
    if (t == 511) bktoff[NBK] = sd[511];
}

__global__ __launch_bounds__(256) void pair_scatter_kernel(
    const int* __restrict__ ei, const int* __restrict__ flags,
    const int* __restrict__ histo, const int* __restrict__ bktoff,
    int2* __restrict__ pairs, int E)
{
    __shared__ int cur[NBK];
    int b = blockIdx.x, t = threadIdx.x;
    for (int j = t; j < NBK; j += 256) cur[j] = histo[j * NHB + b] + bktoff[j];
    __syncthreads();
    int i64 = flags[1];
    int e0 = b * ECHUNK, e1 = min(e0 + ECHUNK, E);
    for (int i = e0 + t; i < e1; i += 256) {
        int d = i64 ? ei[2 * (E + i)] : ei[E + i];
        int s = i64 ? ei[2 * i]       : ei[i];
        int p = atomicAdd(&cur[d >> 8], 1);
        pairs[p] = make_int2(d, s);
    }
}

__global__ __launch_bounds__(256) void bucket_deg_kernel(
    const int2* __restrict__ pairs, const int* __restrict__ bktoff,
    int* __restrict__ deg, int N)
{
    __shared__ int cnt[256];
    int j = blockIdx.x, t = threadIdx.x;
    cnt[t] = 0;
    __syncthreads();
    int e0 = bktoff[j], e1 = bktoff[j + 1];
    for (int i = e0 + t; i < e1; i += 256)
        atomicAdd(&cnt[pairs[i].x & 255], 1);
    __syncthreads();
    int idx = j * 256 + t;
    if (idx < N) deg[idx] = cnt[t];
}

__global__ __launch_bounds__(256) void scan1_kernel(
    const int* __restrict__ deg, int* __restrict__ part, int* __restrict__ bsum, int n)
{
    __shared__ int sd[256];
    int t = threadIdx.x;
    int i0 = blockIdx.x * 1024 + t * 4;
    int v0 = 0, v1 = 0, v2 = 0, v3 = 0;
    if (i0 + 3 < n) {
        int4 v = *(const int4*)(deg + i0);
        v0 = v.x; v1 = v.y; v2 = v.z; v3 = v.w;
    } else if (i0 < n) {
        v0 = deg[i0];
        if (i0 + 1 < n) v1 = deg[i0 + 1];
        if (i0 + 2 < n) v2 = deg[i0 + 2];
    }
    int s = v0 + v1 + v2 + v3;
    sd[t] = s;
    __syncthreads();
    #pragma unroll
    for (int off = 1; off < 256; off <<= 1) {
        int add = (t >= off) ? sd[t - off] : 0;
        __syncthreads();
        sd[t] += add;
        __syncthreads();
    }
    int incl = sd[t];
    int e0 = incl - s;
    int p0 = e0 + v0, p1 = p0 + v1, p2 = p1 + v2, p3 = p2 + v3;
    if (i0 < n)     part[i0]     = p0;
    if (i0 + 1 < n) part[i0 + 1] = p1;
    if (i0 + 2 < n) part[i0 + 2] = p2;
    if (i0 + 3 < n) part[i0 + 3] = p3;
    if (t == 255) bsum[blockIdx.x] = incl;
}

__global__ __launch_bounds__(128) void scan2_kernel(int* __restrict__ bsum, int nb)
{
    __shared__ int sd[128];
    int t = threadIdx.x;
    int own = (t < nb) ? bsum[t] : 0;
    sd[t] = own;
    __syncthreads();
    #pragma unroll
    for (int off = 1; off < 128; off <<= 1) {
        int add = (t >= off) ? sd[t - off] : 0;
        __syncthreads();
        sd[t] += add;
        __syncthreads();
    }
    if (t < nb) bsum[t] = sd[t] - own;
}

__global__ __launch_bounds__(256) void scan3_kernel(
    const int* __restrict__ part, const int* __restrict__ bsum,
    const int* __restrict__ deg, int* __restrict__ indptr,
    float* __restrict__ inv_deg, int n)
{
    int i = blockIdx.x * 256 + threadIdx.x;
    if (i >= n) return;
    int val = part[i] + bsum[i >> 10];
    indptr[i + 1] = val;
    int d = deg[i];
    inv_deg[i] = (d > 0) ? 1.0f / (float)d : 0.0f;
    if (i == 0) indptr[0] = 0;
}

// invg + identity-init of the BN affine (A=1, C=0) for layer 0's agg
__global__ __launch_bounds__(512) void invg_kernel(
    const int* __restrict__ gcnt, float* __restrict__ invg,
    float* __restrict__ ac, int G)
{
    int g = threadIdx.x;
    if (g < G) {
        int c = gcnt[g];
        invg[g] = (c > 0) ? 1.0f / (float)c : 0.0f;
    }
    if (g < 64) ac[g] = 1.0f;
    else if (g < 128) ac[g] = 0.0f;
}

__global__ __launch_bounds__(256) void csr_fill_kernel(
    const int2* __restrict__ pairs, const int* __restrict__ bktoff,
    const int* __restrict__ indptr, int* __restrict__ esrc, int N)
{
    __shared__ int cur[256];
    int j = blockIdx.x, t = threadIdx.x;
    int idx = j * 256 + t;
    cur[t] = (idx < N) ? indptr[idx] : 0;
    __syncthreads();
    int e0 = bktoff[j], e1 = bktoff[j + 1];
    for (int i = e0 + t; i < e1; i += 256) {
        int2 e = pairs[i];
        int p = atomicAdd(&cur[e.x & 255], 1);
        esrc[p] = e.y;
    }
}

// ---------- per-layer ----------
// agg (round 10, unchanged): edge-index broadcast + unrolled gathers,
// zout = A*(z_own + mean(z_nb)) + C*(1+[deg>0])
__global__ __launch_bounds__(256) void agg_kernel(
    const float* __restrict__ zprev, const ushort_t* __restrict__ zb,
    const int* __restrict__ indptr, const int* __restrict__ esrc,
    const float* __restrict__ inv_deg, const float* __restrict__ ac,
    float* __restrict__ zout, int n)
{
    int t = threadIdx.x;
    int grp = t >> 4, l = t & 15;
    int lane = t & 63;
    int gl0 = lane & 48;
    int node = blockIdx.x * 16 + grp;
    if (node >= n) return;
    int e0 = indptr[node], e1 = indptr[node + 1];
    float a0 = 0.f, a1 = 0.f, a2 = 0.f, a3 = 0.f;
    const ushort_t* zbl = zb + l * 4;
    for (int base = e0; base < e1; base += 16) {
        int cnt = e1 - base;
        if (cnt > 16) cnt = 16;
        int myi = (l < cnt) ? esrc[base + l] : 0;
        if (cnt == 16) {
            #pragma unroll
            for (int j = 0; j < 16; ++j) {
                int s = __shfl(myi, gl0 + j, 64);
                uint2 v = *(const uint2*)(zbl + (size_t)s * 64);
                a0 += __uint_as_float(v.x << 16);
                a1 += __uint_as_float(v.x & 0xffff0000u);
                a2 += __uint_as_float(v.y << 16);
                a3 += __uint_as_float(v.y & 0xffff0000u);
            }
        } else {
            for (int j = 0; j < cnt; ++j) {
                int s = __shfl(myi, gl0 + j, 64);
                uint2 v = *(const uint2*)(zbl + (size_t)s * 64);
                a0 += __uint_as_float(v.x << 16);
                a1 += __uint_as_float(v.x & 0xffff0000u);
                a2 += __uint_as_float(v.y << 16);
                a3 += __uint_as_float(v.y & 0xffff0000u);
            }
        }
    }
    float idg = inv_deg[node];
    float cf = (idg > 0.f) ? 2.f : 1.f;
    float4 own = *(const float4*)(zprev + (size_t)node * 64 + l * 4);
    float4 A = *(const float4*)(ac + l * 4);
    float4 C = *(const float4*)(ac + 64 + l * 4);
    float4 r;
    r.x = fmaf(A.x, fmaf(idg, a0, own.x), C.x * cf);
    r.y = fmaf(A.y, fmaf(idg, a1, own.y), C.y * cf);
    r.z = fmaf(A.z, fmaf(idg, a2, own.z), C.z * cf);
    r.w = fmaf(A.w, fmaf(idg, a3, own.w), C.w * cf);
    *(float4*)(zout + (size_t)node * 64 + l * 4) = r;
}

// MLP: 4 lanes per node, each owns 16 features. Shared operands broadcast
// via __shfl within the 4-lane group; same k-order FMA chain as round 10.
__global__ __launch_bounds__(256, 2) void mlp_kernel(
    float* __restrict__ zf, ushort_t* __restrict__ zb,
    const float* __restrict__ W1f, const float* __restrict__ b1f,
    const float* __restrict__ W2f, const float* __restrict__ b2f,
    int n)
{
    __shared__ float w1s[4096];
    __shared__ float w2s[4096];
    __shared__ float bs[128];
    int t = threadIdx.x;
    for (int i = t; i < 4096; i += 256) {
        w1s[i] = W1f[i];
        w2s[i] = W2f[i];
    }
    if (t < 64) bs[t] = b1f[t];
    else if (t < 128) bs[t] = b2f[t - 64];
    __syncthreads();

    int idx = blockIdx.x * 256 + t;
    int node = idx >> 2;
    if (node >= n) return;
    int sub = t & 3;
    int lane = t & 63;
    int grp = lane & ~3;          // base lane of my 4-lane group
    int j0 = sub * 16;
    float* zrow = zf + (size_t)node * 64;
    ushort_t* zbrow = zb + (size_t)node * 64;

    // my quarter of z
    float zc[16];
    {
        const float4* zp = (const float4*)(zrow + j0);
        #pragma unroll
        for (int q = 0; q < 4; ++q) {
            float4 v = zp[q];
            zc[4*q] = v.x; zc[4*q+1] = v.y; zc[4*q+2] = v.z; zc[4*q+3] = v.w;
        }
    }

    // GEMM1: y[j0..j0+16)
    float y[16];
    #pragma unroll
    for (int q = 0; q < 16; ++q) y[q] = bs[j0 + q];
    #pragma unroll
    for (int k = 0; k < 64; ++k) {
        float a = __shfl(zc[k & 15], grp + (k >> 4), 64);
        const float4* w = (const float4*)(w1s + k * 64 + j0);
        #pragma unroll
        for (int q = 0; q < 4; ++q) {
            float4 wv = w[q];
            y[4*q]   = fmaf(a, wv.x, y[4*q]);
            y[4*q+1] = fmaf(a, wv.y, y[4*q+1]);
            y[4*q+2] = fmaf(a, wv.z, y[4*q+2]);
            y[4*q+3] = fmaf(a, wv.w, y[4*q+3]);
        }
    }
    #pragma unroll
    for (int q = 0; q < 16; ++q) y[q] = fmaxf(y[q], 0.f);

    // GEMM2: o[j0..j0+16)
    float o[16];
    #pragma unroll
    for (int q = 0; q < 16; ++q) o[q] = bs[64 + j0 + q];
    #pragma unroll
    for (int k = 0; k < 64; ++k) {
        float a = __shfl(y[k & 15], grp + (k >> 4), 64);
        const float4* w = (const float4*)(w2s + k * 64 + j0);
        #pragma unroll
        for (int q = 0; q < 4; ++q) {
            float4 wv = w[q];
            o[4*q]   = fmaf(a, wv.x, o[4*q]);
            o[4*q+1] = fmaf(a, wv.y, o[4*q+1]);
            o[4*q+2] = fmaf(a, wv.z, o[4*q+2]);
            o[4*q+3] = fmaf(a, wv.w, o[4*q+3]);
        }
    }

    // relu + store fp32 + bf16 mirror (group-contiguous)
    #pragma unroll
    for (int q = 0; q < 4; ++q) {
        float4 v;
        v.x = fmaxf(o[4*q],   0.f);
        v.y = fmaxf(o[4*q+1], 0.f);
        v.z = fmaxf(o[4*q+2], 0.f);
        v.w = fmaxf(o[4*q+3], 0.f);
        *(float4*)(zrow + j0 + q * 4) = v;
        __hip_bfloat16 p0 = __float2bfloat16(v.x);
        __hip_bfloat16 p1 = __float2bfloat16(v.y);
        __hip_bfloat16 p2 = __float2bfloat16(v.z);
        __hip_bfloat16 p3 = __float2bfloat16(v.w);
        uint2 pw;
        pw.x = (uint_t)*(ushort_t*)&p0 | ((uint_t)*(ushort_t*)&p1 << 16);
        pw.y = (uint_t)*(ushort_t*)&p2 | ((uint_t)*(ushort_t*)&p3 << 16);
        *(uint2*)(zbrow + j0 + q * 4) = pw;
    }
}

// per-feature sum / sumsq -> float atomics (128 addresses)
__global__ __launch_bounds__(256) void stats_kernel(
    const float* __restrict__ z, float* __restrict__ stats, int N)
{
    __shared__ float ssum[256], ssq[256];
    int t = threadIdx.x;
    float s = 0.f, q = 0.f;
    int total = N * 64;
    for (int i = blockIdx.x * 256 + t; i < total; i += 256 * gridDim.x) {
        float v = z[i];
        s += v;
        q += v * v;
    }
    ssum[t] = s; ssq[t] = q;
    __syncthreads();
    if (t < 64) {
        float S = ssum[t] + ssum[t+64] + ssum[t+128] + ssum[t+192];
        float Q = ssq[t]  + ssq[t+64]  + ssq[t+128]  + ssq[t+192];
        atomicAdd(&stats[t], S);
        atomicAdd(&stats[64 + t], Q);
    }
}

__global__ __launch_bounds__(64) void bnfin_kernel(
    const float* __restrict__ stats, const float* __restrict__ gammaf,
    const float* __restrict__ betaf, float* __restrict__ ac, int N)
{
    int f = threadIdx.x;
    if (f >= 64) return;
    float invN = 1.0f / (float)N;
    float mu = stats[f] * invN;
    float var = stats[64 + f] * invN - mu * mu;
    if (var < 0.f) var = 0.f;
    float inv = rsqrtf(var + 1e-5f);
    float A = gammaf[f] * inv;
    float C = betaf[f] - mu * A;
    ac[f] = A;
    ac[64 + f] = C;
}

// pools only: h = A*z + C on the fly; node_pool (+=), gpool run-length atomics
__global__ __launch_bounds__(256) void pool_kernel(
    const float* __restrict__ z, float* __restrict__ node_pool,
    const int* __restrict__ b32, const float* __restrict__ ac,
    float* __restrict__ gpool, int N, int first)
{
    int wave = (blockIdx.x * 256 + threadIdx.x) >> 6;
    int f = threadIdx.x & 63;
    int n0 = wave * 64;
    if (n0 >= N) return;
    int n1 = min(n0 + 64, N);
    float A = ac[f], C = ac[64 + f];
    float racc = 0.f;
    int cur = b32[n0];
    for (int n = n0; n < n1; ++n) {
        int g = b32[n];
        if (g != cur) {  // wave-uniform branch
            atomicAdd(&gpool[(size_t)cur * 64 + f], racc);
            racc = 0.f;
            cur = g;
        }
        size_t idx = (size_t)n * 64 + f;
        float hv = fmaf(z[idx], A, C);
        float np = first ? hv : (node_pool[idx] + hv);
        node_pool[idx] = np;
        racc += hv;
    }
    atomicAdd(&gpool[(size_t)cur * 64 + f], racc);
}

__global__ __launch_bounds__(256) void finalize_kernel(
    const float* __restrict__ node_pool, const float* __restrict__ gpool,
    const float* __restrict__ invg, const int* __restrict__ flags,
    void* __restrict__ out, int N)
{
    int i = blockIdx.x * 256 + threadIdx.x;
    int nd = N * 64;
    int total = nd + GG * 64;
    if (i >= total) return;
    float v;
    if (i < nd) v = node_pool[i];
    else { int j = i - nd; v = gpool[j] * invg[j >> 6]; }
    if (flags[0]) ((float*)out)[i] = v;
    else ((__hip_bfloat16*)out)[i] = __float2bfloat16(v);
}

extern "C" void kernel_launch(void* const* d_in, const int* in_sizes, int n_in,
                              void* d_out, int out_size, void* d_ws, size_t ws_size,
                              hipStream_t stream)
{
    constexpr int N = NN, E = EE, G = GG;
    constexpr int ND = N * 64;

    const void* x     = d_in[0];
    const void* W1    = d_in[1];
    const void* b1    = d_in[2];
    const void* W2    = d_in[3];
    const void* b2    = d_in[4];
    const void* gamma = d_in[5];
    const void* beta  = d_in[6];
    const int* ei     = (const int*)d_in[7];
    const int* batw   = (const int*)d_in[8];

    char* p = (char*)d_ws;
    auto alloc = [&](size_t bytes) -> char* {
        char* r = p;
        p += (bytes + 255) & ~(size_t)255;
        return r;
    };
    float*    zbufA     = (float*)alloc((size_t)ND * 4);
    float*    zbufB     = (float*)alloc((size_t)ND * 4);
    float*    node_pool = (float*)alloc((size_t)ND * 4);
    ushort_t* zb        = (ushort_t*)alloc((size_t)ND * 2);
    int*      esrc      = (int*)alloc((size_t)E * 4);
    int*      indptr    = (int*)alloc((size_t)(N + 1) * 4);
    int*      deg       = (int*)alloc((size_t)N * 4);
    int*      part      = (int*)alloc((size_t)N * 4);
    float*    invdeg    = (float*)alloc((size_t)N * 4);
    int*      b32       = (int*)alloc((size_t)N * 4);
    int*      bsum      = (int*)alloc(128 * 4);
    int*      gcnt      = (int*)alloc(G * 4);
    float*    invg      = (float*)alloc(G * 4);
    float*    gpool     = (float*)alloc((size_t)G * 64 * 4);
    float*    stats     = (float*)alloc(128 * 4);
    float*    ac        = (float*)alloc(128 * 4);
    float*    wf        = (float*)alloc(33792 * 4);
    int*      flags     = (int*)alloc(16 * 4);
    int*      histo     = (int*)alloc((size_t)NBK * NHB * 4);
    int*      tot       = (int*)alloc((size_t)NBK * 4);
    int*      bktoff    = (int*)alloc((size_t)(NBK + 1) * 4);
    // pairs aliases node_pool: dead until first pool_kernel; E*8 == ND*4 bytes
    int2*     pairs     = (int2*)node_pool;

    hipMemsetAsync(gcnt,  0, (size_t)G * 4,      stream);
    hipMemsetAsync(gpool, 0, (size_t)G * 64 * 4, stream);

    detect_kernel<<<1, 256, 0, stream>>>(
        (const uint_t*)x, (const uint_t*)ei, (const uint_t*)batw, flags);
    cvt_w_kernel<<<132, 256, 0, stream>>>(W1, b1, W2, b2, gamma, beta, flags, wf);
    cvt_x_kernel<<<(ND + 255) / 256, 256, 0, stream>>>(x, flags, zbufA, zb, ND);
    cvt_batch_kernel<<<(N + 255) / 256, 256, 0, stream>>>(batw, flags, b32, gcnt, N);
    count_hist_kernel<<<NHB, 256, 0, stream>>>(ei, flags, histo, E);
    blockscan_kernel<<<NBK, NHB, 0, stream>>>(histo, tot);
    bscan_kernel<<<1, 512, 0, stream>>>(tot, bktoff);
    pair_scatter_kernel<<<NHB, 256, 0, stream>>>(ei, flags, histo, bktoff, pairs, E);
    bucket_deg_kernel<<<NBK, 256, 0, stream>>>(pairs, bktoff, deg, N);
    int nb = (N + 1023) / 1024;  // 98
    scan1_kernel<<<nb, 256, 0, stream>>>(deg, part, bsum, N);
    scan2_kernel<<<1, 128, 0, stream>>>(bsum, nb);
    scan3_kernel<<<(N + 255) / 256, 256, 0, stream>>>(part, bsum, deg, indptr, invdeg, N);
    invg_kernel<<<1, 512, 0, stream>>>(gcnt, invg, ac, G);
    csr_fill_kernel<<<NBK, 256, 0, stream>>>(pairs, bktoff, indptr, esrc, N);

    float* zin = zbufA;
    float* zout = zbufB;
    for (int l = 0; l < 4; ++l) {
        agg_kernel<<<(N + 15) / 16, 256, 0, stream>>>(
            zin, zb, indptr, esrc, invdeg, ac, zout, N);
        mlp_kernel<<<(N * 4 + 255) / 256, 256, 0, stream>>>(
            zout, zb, wf + l * 4096, wf + 32768 + l * 64,
            wf + 16384 + l * 4096, wf + 33024 + l * 64, N);
        hipMemsetAsync(stats, 0, 128 * 4, stream);
        stats_kernel<<<256, 256, 0, stream>>>(zout, stats, N);
        bnfin_kernel<<<1, 64, 0, stream>>>(
            stats, wf + 33280 + l * 64, wf + 33536 + l * 64, ac, N);
        pool_kernel<<<(N + 255) / 256, 256, 0, stream>>>(
            zout, node_pool, b32, ac, gpool, N, (l == 0) ? 1 : 0);
        float* tmp = zin; zin = zout; zout = tmp;
    }
    finalize_kernel<<<(ND + G * 64 + 255) / 256, 256, 0, stream>>>(
        node_pool, gpool, invg, flags, d_out, N);
}